// Round 1
// baseline (1540.237 us; speedup 1.0000x reference)
//
#include <hip/hip_runtime.h>
#include <hip/hip_bf16.h>
#include <math.h>

#define B_DIM 2
#define L_DIM 1024
#define DM 1024
#define DI 2048
#define NS 64

// ---------------- RMSNorm row factors (norm fused into GEMM0 staging) --------
__global__ __launch_bounds__(256) void k_rmsfac(const float* __restrict__ x,
                                                float* __restrict__ rinv)
{
    int row = blockIdx.x;
    float4 v = ((const float4*)(x + (size_t)row * DM))[threadIdx.x];
    float ss = v.x*v.x + v.y*v.y + v.z*v.z + v.w*v.w;
    #pragma unroll
    for (int m = 32; m; m >>= 1) ss += __shfl_xor(ss, m, 64);
    __shared__ float red[4];
    if ((threadIdx.x & 63) == 0) red[threadIdx.x >> 6] = ss;
    __syncthreads();
    if (threadIdx.x == 0) {
        float tot = red[0] + red[1] + red[2] + red[3];
        rinv[row] = rsqrtf(tot * (1.0f / DM) + 1e-6f);
    }
}

// ---------------- NT GEMM: C[m][n] = sum_k A[m][k] * Bw[n][k] ----------------
// MODE 0: A = x scaled by rinv[m]*norm_w[k]; C0 = xr [2048][4096]
// MODE 1: nt<32 : Bw0=dt_w,   C0 = dt = softplus(acc + dt_b) [2048][2048]
//         nt==32: Bw1=x_proj_w+64*2048, C1 = B_ssm [2048][64]
// MODE 2: Bw0=out_proj_w, C0 = out = acc + skip   [2048][1024]
template<int MODE>
__global__ __launch_bounds__(256) void k_gemm(
    const float* __restrict__ A, const float* __restrict__ Bw0,
    const float* __restrict__ Bw1,
    float* __restrict__ C0, float* __restrict__ C1,
    const float* __restrict__ bias, const float* __restrict__ skip,
    const float* __restrict__ rinv, const float* __restrict__ normw, int Kdim)
{
    __shared__ float As[32][68];   // k-major, pad 68 words (16B aligned rows)
    __shared__ float Bs[32][68];
    const int t = threadIdx.x;
    const int nt = blockIdx.x, mt = blockIdx.y;
    const int mBase = mt * 64;
    const bool isXP = (MODE == 1) && (nt == 32);
    const float* __restrict__ Bw = isXP ? Bw1 : Bw0;
    const int nBaseB = isXP ? 0 : nt * 64;
    const int tx = t & 15, ty = t >> 4;
    float acc[4][4] = {};

    for (int kt = 0; kt < Kdim; kt += 32) {
        #pragma unroll
        for (int s = 0; s < 2; ++s) {
            int id = t + s * 256;
            int r = id >> 3, kq = id & 7;
            int kcol = kt + kq * 4;
            float4 va = *(const float4*)(A + (size_t)(mBase + r) * Kdim + kcol);
            if constexpr (MODE == 0) {
                float ri = rinv[mBase + r];
                float4 nw = *(const float4*)(normw + kcol);
                va.x *= ri * nw.x; va.y *= ri * nw.y;
                va.z *= ri * nw.z; va.w *= ri * nw.w;
            }
            As[kq*4+0][r] = va.x; As[kq*4+1][r] = va.y;
            As[kq*4+2][r] = va.z; As[kq*4+3][r] = va.w;
            float4 vb = *(const float4*)(Bw + (size_t)(nBaseB + r) * Kdim + kcol);
            Bs[kq*4+0][r] = vb.x; Bs[kq*4+1][r] = vb.y;
            Bs[kq*4+2][r] = vb.z; Bs[kq*4+3][r] = vb.w;
        }
        __syncthreads();
        #pragma unroll
        for (int kk = 0; kk < 32; ++kk) {
            float4 a4 = *(const float4*)&As[kk][ty * 4];
            float4 b4 = *(const float4*)&Bs[kk][tx * 4];
            float av[4] = {a4.x, a4.y, a4.z, a4.w};
            float bv[4] = {b4.x, b4.y, b4.z, b4.w};
            #pragma unroll
            for (int i = 0; i < 4; ++i)
                #pragma unroll
                for (int j = 0; j < 4; ++j)
                    acc[i][j] = fmaf(av[i], bv[j], acc[i][j]);
        }
        __syncthreads();
    }

    const int col = (isXP ? 0 : nt * 64) + tx * 4;
    #pragma unroll
    for (int i = 0; i < 4; ++i) {
        int m = mBase + ty * 4 + i;
        if constexpr (MODE == 0) {
            float4 o = make_float4(acc[i][0], acc[i][1], acc[i][2], acc[i][3]);
            *(float4*)(C0 + (size_t)m * (2*DI) + col) = o;
        } else if constexpr (MODE == 1) {
            if (isXP) {
                float4 o = make_float4(acc[i][0], acc[i][1], acc[i][2], acc[i][3]);
                *(float4*)(C1 + (size_t)m * NS + col) = o;
            } else {
                float o[4];
                #pragma unroll
                for (int j = 0; j < 4; ++j) {
                    float z = acc[i][j] + bias[col + j];
                    o[j] = (z > 20.f) ? z : logf(1.f + expf(z));
                }
                float4 ov = make_float4(o[0], o[1], o[2], o[3]);
                *(float4*)(C0 + (size_t)m * DI + col) = ov;
            }
        } else {
            float4 sk = *(const float4*)(skip + (size_t)m * DM + col);
            float4 o = make_float4(acc[i][0] + sk.x, acc[i][1] + sk.y,
                                   acc[i][2] + sk.z, acc[i][3] + sk.w);
            *(float4*)(C0 + (size_t)m * DM + col) = o;
        }
    }
}

// ---------------- causal depthwise conv1d (K=4) + SiLU -----------------------
__global__ __launch_bounds__(256) void k_conv(const float* __restrict__ xr,
    const float* __restrict__ cw, const float* __restrict__ cb,
    float* __restrict__ xc)
{
    int gid = blockIdx.x * 256 + threadIdx.x;      // [0, 2*1024*512)
    int d = (gid & 511) * 4;
    int tt = (gid >> 9) & 1023;
    int b = gid >> 19;
    float4 w[4];
    #pragma unroll
    for (int c = 0; c < 4; ++c) w[c] = *(const float4*)(cw + (size_t)(d + c) * 4);
    float4 acc = *(const float4*)(cb + d);
    const float* base = xr + (size_t)b * L_DIM * (2*DI) + d;
    #pragma unroll
    for (int j = 0; j < 4; ++j) {
        int ti = tt - 3 + j;
        if (ti < 0) continue;
        float4 xv = *(const float4*)(base + (size_t)ti * (2*DI));
        const float* w0 = (const float*)&w[0];
        const float* w1 = (const float*)&w[1];
        const float* w2 = (const float*)&w[2];
        const float* w3 = (const float*)&w[3];
        acc.x = fmaf(w0[j], xv.x, acc.x);
        acc.y = fmaf(w1[j], xv.y, acc.y);
        acc.z = fmaf(w2[j], xv.z, acc.z);
        acc.w = fmaf(w3[j], xv.w, acc.w);
    }
    acc.x = acc.x / (1.f + expf(-acc.x));
    acc.y = acc.y / (1.f + expf(-acc.y));
    acc.z = acc.z / (1.f + expf(-acc.z));
    acc.w = acc.w / (1.f + expf(-acc.w));
    *(float4*)(xc + (size_t)(b * L_DIM + tt) * DI + d) = acc;
}

// ---------------- selective scan: wave per (b,d), lane = state n -------------
__global__ __launch_bounds__(256) void k_scan(const float* __restrict__ xc,
    const float* __restrict__ dtb, const float* __restrict__ Bss,
    const float* __restrict__ A_log, const float* __restrict__ Dp,
    const float* __restrict__ xr, float* __restrict__ y)
{
    int wv = (blockIdx.x * 256 + threadIdx.x) >> 6;   // 0..4095
    int lane = threadIdx.x & 63;
    int b = wv >> 11;
    int d = wv & 2047;
    float aL2 = -expf(A_log[(size_t)d * NS + lane]) * 1.44269504f; // A*log2(e)
    float Dv = Dp[d];
    float h = 0.f;
    const float* dtp  = dtb + (size_t)b * L_DIM * DI + d;
    const float* xcp  = xc  + (size_t)b * L_DIM * DI + d;
    const float* Bp   = Bss + (size_t)b * L_DIM * NS + lane;
    const float* resp = xr  + (size_t)b * L_DIM * (2*DI) + DI + d;
    float* yp = y + (size_t)b * L_DIM * DI + d;
    for (int t = 0; t < L_DIM; ++t) {
        float dtv = dtp[(size_t)t * DI];
        float xv  = xcp[(size_t)t * DI];
        float Bv  = Bp[(size_t)t * NS];
        float ad = exp2f(aL2 * dtv);              // exp(A*dt)
        h = fmaf(ad, h, Bv * xv);
        float s = h;
        #pragma unroll
        for (int m = 32; m; m >>= 1) s += __shfl_xor(s, m, 64);
        if (lane == 0) {
            float rv = resp[(size_t)t * (2*DI)];
            float sig = rv / (1.f + expf(-rv));   // silu(res)
            yp[(size_t)t * DI] = (s + Dv * xv) * sig;
        }
    }
}

extern "C" void kernel_launch(void* const* d_in, const int* in_sizes, int n_in,
                              void* d_out, int out_size, void* d_ws, size_t ws_size,
                              hipStream_t stream)
{
    const float* x        = (const float*)d_in[0];
    const float* norm_w   = (const float*)d_in[1];
    const float* in_projw = (const float*)d_in[2];
    const float* conv_w   = (const float*)d_in[3];
    const float* conv_b   = (const float*)d_in[4];
    const float* x_projw  = (const float*)d_in[5];
    const float* dt_w     = (const float*)d_in[6];
    const float* dt_b     = (const float*)d_in[7];
    const float* A_log    = (const float*)d_in[8];
    const float* D_param  = (const float*)d_in[9];
    const float* out_projw= (const float*)d_in[10];
    float* out = (float*)d_out;

    float* ws   = (float*)d_ws;
    float* rinv = ws;                               // 2048
    float* xr   = rinv + 2048;                      // 2048*4096
    float* xc   = xr  + (size_t)2048 * 4096;        // 2048*2048
    float* dtb  = xc  + (size_t)2048 * 2048;        // 2048*2048
    float* Bss  = dtb + (size_t)2048 * 2048;        // 2048*64
    float* y    = Bss + (size_t)2048 * 64;          // 2048*2048

    k_rmsfac<<<2048, 256, 0, stream>>>(x, rinv);
    k_gemm<0><<<dim3(64, 32), 256, 0, stream>>>(x, in_projw, nullptr, xr, nullptr,
                                                nullptr, nullptr, rinv, norm_w, 1024);
    k_conv<<<4096, 256, 0, stream>>>(xr, conv_w, conv_b, xc);
    k_gemm<1><<<dim3(33, 32), 256, 0, stream>>>(xc, dt_w, x_projw + (size_t)64*2048,
                                                dtb, Bss, dt_b, nullptr, nullptr, nullptr, 2048);
    k_scan<<<1024, 256, 0, stream>>>(xc, dtb, Bss, A_log, D_param, xr, y);
    k_gemm<2><<<dim3(16, 32), 256, 0, stream>>>(y, out_projw, nullptr, out, nullptr,
                                                nullptr, x, nullptr, nullptr, 2048);
}

// Round 2
// 1308.193 us; speedup vs baseline: 1.1774x; 1.1774x over previous
//
#include <hip/hip_runtime.h>
#include <hip/hip_bf16.h>
#include <math.h>

#define B_DIM 2
#define L_DIM 1024
#define DM 1024
#define DI 2048
#define NS 64

// ---------------- RMSNorm row factors (norm fused into GEMM0 staging) --------
__global__ __launch_bounds__(256) void k_rmsfac(const float* __restrict__ x,
                                                float* __restrict__ rinv)
{
    int row = blockIdx.x;
    float4 v = ((const float4*)(x + (size_t)row * DM))[threadIdx.x];
    float ss = v.x*v.x + v.y*v.y + v.z*v.z + v.w*v.w;
    #pragma unroll
    for (int m = 32; m; m >>= 1) ss += __shfl_xor(ss, m, 64);
    __shared__ float red[4];
    if ((threadIdx.x & 63) == 0) red[threadIdx.x >> 6] = ss;
    __syncthreads();
    if (threadIdx.x == 0) {
        float tot = red[0] + red[1] + red[2] + red[3];
        rinv[row] = rsqrtf(tot * (1.0f / DM) + 1e-6f);
    }
}

// ---------------- NT GEMM: C[m][n] = sum_k A[m][k] * Bw[n][k] ----------------
// MODE 0: A = x scaled by rinv[m]*norm_w[k]; C0 = xr [2048][4096]
// MODE 1: nt<32 : Bw0=dt_w,   C0 = dt = softplus(acc + dt_b) [2048][2048]
//         nt==32: Bw1=x_proj_w+64*2048, C1 = B_ssm [2048][64]
// MODE 2: A = y gated by silu(res) from gate rows; C0 = out = acc + skip
template<int MODE>
__global__ __launch_bounds__(256) void k_gemm(
    const float* __restrict__ A, const float* __restrict__ Bw0,
    const float* __restrict__ Bw1,
    float* __restrict__ C0, float* __restrict__ C1,
    const float* __restrict__ bias, const float* __restrict__ skip,
    const float* __restrict__ rinv, const float* __restrict__ normw,
    const float* __restrict__ gate, int Kdim)
{
    __shared__ float As[32][68];   // k-major
    __shared__ float Bs[32][68];
    const int t = threadIdx.x;
    const int nt = blockIdx.x, mt = blockIdx.y;
    const int mBase = mt * 64;
    const bool isXP = (MODE == 1) && (nt == 32);
    const float* __restrict__ Bw = isXP ? Bw1 : Bw0;
    const int nBaseB = isXP ? 0 : nt * 64;
    const int tx = t & 15, ty = t >> 4;
    float acc[4][4] = {};

    for (int kt = 0; kt < Kdim; kt += 32) {
        #pragma unroll
        for (int s = 0; s < 2; ++s) {
            int id = t + s * 256;
            int r = id >> 3, kq = id & 7;
            int kcol = kt + kq * 4;
            float4 va = *(const float4*)(A + (size_t)(mBase + r) * Kdim + kcol);
            if constexpr (MODE == 0) {
                float ri = rinv[mBase + r];
                float4 nw = *(const float4*)(normw + kcol);
                va.x *= ri * nw.x; va.y *= ri * nw.y;
                va.z *= ri * nw.z; va.w *= ri * nw.w;
            }
            if constexpr (MODE == 2) {
                float4 rv = *(const float4*)(gate + (size_t)(mBase + r) * (2*DI) + DI + kcol);
                va.x *= rv.x / (1.f + __expf(-rv.x));
                va.y *= rv.y / (1.f + __expf(-rv.y));
                va.z *= rv.z / (1.f + __expf(-rv.z));
                va.w *= rv.w / (1.f + __expf(-rv.w));
            }
            As[kq*4+0][r] = va.x; As[kq*4+1][r] = va.y;
            As[kq*4+2][r] = va.z; As[kq*4+3][r] = va.w;
            float4 vb = *(const float4*)(Bw + (size_t)(nBaseB + r) * Kdim + kcol);
            Bs[kq*4+0][r] = vb.x; Bs[kq*4+1][r] = vb.y;
            Bs[kq*4+2][r] = vb.z; Bs[kq*4+3][r] = vb.w;
        }
        __syncthreads();
        #pragma unroll
        for (int kk = 0; kk < 32; ++kk) {
            float4 a4 = *(const float4*)&As[kk][ty * 4];
            float4 b4 = *(const float4*)&Bs[kk][tx * 4];
            float av[4] = {a4.x, a4.y, a4.z, a4.w};
            float bv[4] = {b4.x, b4.y, b4.z, b4.w};
            #pragma unroll
            for (int i = 0; i < 4; ++i)
                #pragma unroll
                for (int j = 0; j < 4; ++j)
                    acc[i][j] = fmaf(av[i], bv[j], acc[i][j]);
        }
        __syncthreads();
    }

    const int col = (isXP ? 0 : nt * 64) + tx * 4;
    #pragma unroll
    for (int i = 0; i < 4; ++i) {
        int m = mBase + ty * 4 + i;
        if constexpr (MODE == 0) {
            float4 o = make_float4(acc[i][0], acc[i][1], acc[i][2], acc[i][3]);
            *(float4*)(C0 + (size_t)m * (2*DI) + col) = o;
        } else if constexpr (MODE == 1) {
            if (isXP) {
                float4 o = make_float4(acc[i][0], acc[i][1], acc[i][2], acc[i][3]);
                *(float4*)(C1 + (size_t)m * NS + col) = o;
            } else {
                float o[4];
                #pragma unroll
                for (int j = 0; j < 4; ++j) {
                    float z = acc[i][j] + bias[col + j];
                    o[j] = (z > 20.f) ? z : logf(1.f + expf(z));
                }
                float4 ov = make_float4(o[0], o[1], o[2], o[3]);
                *(float4*)(C0 + (size_t)m * DI + col) = ov;
            }
        } else {
            float4 sk = *(const float4*)(skip + (size_t)m * DM + col);
            float4 o = make_float4(acc[i][0] + sk.x, acc[i][1] + sk.y,
                                   acc[i][2] + sk.z, acc[i][3] + sk.w);
            *(float4*)(C0 + (size_t)m * DM + col) = o;
        }
    }
}

// ---------------- causal depthwise conv1d (K=4) + SiLU -----------------------
__global__ __launch_bounds__(256) void k_conv(const float* __restrict__ xr,
    const float* __restrict__ cw, const float* __restrict__ cb,
    float* __restrict__ xc)
{
    int gid = blockIdx.x * 256 + threadIdx.x;      // [0, 2*1024*512)
    int d = (gid & 511) * 4;
    int tt = (gid >> 9) & 1023;
    int b = gid >> 19;
    float4 w[4];
    #pragma unroll
    for (int c = 0; c < 4; ++c) w[c] = *(const float4*)(cw + (size_t)(d + c) * 4);
    float4 acc = *(const float4*)(cb + d);
    const float* base = xr + (size_t)b * L_DIM * (2*DI) + d;
    #pragma unroll
    for (int j = 0; j < 4; ++j) {
        int ti = tt - 3 + j;
        if (ti < 0) continue;
        float4 xv = *(const float4*)(base + (size_t)ti * (2*DI));
        const float* w0 = (const float*)&w[0];
        const float* w1 = (const float*)&w[1];
        const float* w2 = (const float*)&w[2];
        const float* w3 = (const float*)&w[3];
        acc.x = fmaf(w0[j], xv.x, acc.x);
        acc.y = fmaf(w1[j], xv.y, acc.y);
        acc.z = fmaf(w2[j], xv.z, acc.z);
        acc.w = fmaf(w3[j], xv.w, acc.w);
    }
    acc.x = acc.x / (1.f + expf(-acc.x));
    acc.y = acc.y / (1.f + expf(-acc.y));
    acc.z = acc.z / (1.f + expf(-acc.z));
    acc.w = acc.w / (1.f + expf(-acc.w));
    *(float4*)(xc + (size_t)(b * L_DIM + tt) * DI + d) = acc;
}

// ---------------- tiled transpose: dst[c][r] = src[r][c], batched ------------
__global__ __launch_bounds__(256) void k_tr(const float* __restrict__ src,
    float* __restrict__ dst, int srs, int drs, size_t sB, size_t dB)
{
    __shared__ float tile[64][65];
    const int r0 = blockIdx.y * 64, c0 = blockIdx.x * 64;
    const float* s = src + blockIdx.z * sB;
    float* d = dst + blockIdx.z * dB;
    const int tx = threadIdx.x & 15, ty = threadIdx.x >> 4;
    #pragma unroll
    for (int p = 0; p < 4; ++p) {
        float4 v = *(const float4*)(s + (size_t)(r0 + ty + p*16) * srs + c0 + tx*4);
        tile[ty + p*16][tx*4+0] = v.x; tile[ty + p*16][tx*4+1] = v.y;
        tile[ty + p*16][tx*4+2] = v.z; tile[ty + p*16][tx*4+3] = v.w;
    }
    __syncthreads();
    #pragma unroll
    for (int p = 0; p < 4; ++p) {
        int oc = ty + p*16;                       // local c index
        float4 v = make_float4(tile[tx*4+0][oc], tile[tx*4+1][oc],
                               tile[tx*4+2][oc], tile[tx*4+3][oc]);
        *(float4*)(d + (size_t)(c0 + oc) * drs + r0 + tx*4) = v;
    }
}

// ---------------- selective scan v2: wave per (b,d), lane = state n ----------
// dtt, xct: [b][d][t]; Bss: [b][t][n]; output yt: [b][d][t] = h.sum + D*x
__global__ __launch_bounds__(256) void k_scan2(const float* __restrict__ dtt,
    const float* __restrict__ xct, const float* __restrict__ Bss,
    const float* __restrict__ A_log, const float* __restrict__ Dp,
    float* __restrict__ yt)
{
    __shared__ float Bs[64][68];
    const int lane = threadIdx.x & 63;
    const int widx = threadIdx.x >> 6;
    const int b = blockIdx.x >> 9;
    const int d = (blockIdx.x & 511) * 4 + widx;
    const float aL2 = -expf(A_log[(size_t)d * NS + lane]) * 1.44269504f;
    const float Dv = Dp[d];
    const float* dtp = dtt + ((size_t)b * DI + d) * L_DIM;
    const float* xcp = xct + ((size_t)b * DI + d) * L_DIM;
    const float* Bp  = Bss + (size_t)b * L_DIM * NS;
    float* yp = yt + ((size_t)b * DI + d) * L_DIM;
    const int lr = threadIdx.x >> 2;          // 0..63: B row
    const int lc = (threadIdx.x & 3) * 16;    // B col base
    float h = 0.f;

    for (int t0 = 0; t0 < L_DIM; t0 += 64) {
        const float* bsrc = Bp + (size_t)(t0 + lr) * NS + lc;
        float4 b0 = *(const float4*)(bsrc);
        float4 b1 = *(const float4*)(bsrc + 4);
        float4 b2 = *(const float4*)(bsrc + 8);
        float4 b3 = *(const float4*)(bsrc + 12);
        float dt_v = dtp[t0 + lane];
        float xc_v = xcp[t0 + lane];
        __syncthreads();                       // prev chunk reads complete
        *(float4*)&Bs[lr][lc]      = b0;
        *(float4*)&Bs[lr][lc + 4]  = b1;
        *(float4*)&Bs[lr][lc + 8]  = b2;
        *(float4*)&Bs[lr][lc + 12] = b3;
        __syncthreads();
        float y_v = 0.f;
        #pragma unroll
        for (int tt = 0; tt < 64; ++tt) {
            float dts = __shfl(dt_v, tt, 64);
            float xs  = __shfl(xc_v, tt, 64);
            float ad = exp2f(aL2 * dts);
            float Bv = Bs[tt][lane];
            h = fmaf(ad, h, Bv * xs);
            float s = h;
            #pragma unroll
            for (int m = 32; m; m >>= 1) s += __shfl_xor(s, m, 64);
            if (lane == tt) y_v = s + Dv * xs;
        }
        yp[t0 + lane] = y_v;
    }
}

extern "C" void kernel_launch(void* const* d_in, const int* in_sizes, int n_in,
                              void* d_out, int out_size, void* d_ws, size_t ws_size,
                              hipStream_t stream)
{
    const float* x        = (const float*)d_in[0];
    const float* norm_w   = (const float*)d_in[1];
    const float* in_projw = (const float*)d_in[2];
    const float* conv_w   = (const float*)d_in[3];
    const float* conv_b   = (const float*)d_in[4];
    const float* x_projw  = (const float*)d_in[5];
    const float* dt_w     = (const float*)d_in[6];
    const float* dt_b     = (const float*)d_in[7];
    const float* A_log    = (const float*)d_in[8];
    const float* D_param  = (const float*)d_in[9];
    const float* out_projw= (const float*)d_in[10];
    float* out = (float*)d_out;

    float* ws   = (float*)d_ws;
    float* rinv = ws;                               // 2048
    float* xr   = rinv + 2048;                      // 2048*4096
    float* xc   = xr  + (size_t)2048 * 4096;        // 2048*2048 (reused as y)
    float* dtb  = xc  + (size_t)2048 * 2048;        // 2048*2048 (reused as y_t)
    float* Bss  = dtb + (size_t)2048 * 2048;        // 2048*64
    float* dtt  = Bss + (size_t)2048 * 64;          // 2*2048*1024
    float* xct  = dtt + (size_t)2*2048*1024;        // 2*2048*1024
    float* yt   = dtb;                              // alias (dtb dead after transpose)
    float* y    = xc;                               // alias (xc dead after transposes)

    k_rmsfac<<<2048, 256, 0, stream>>>(x, rinv);
    k_gemm<0><<<dim3(64, 32), 256, 0, stream>>>(x, in_projw, nullptr, xr, nullptr,
                                                nullptr, nullptr, rinv, norm_w, nullptr, 1024);
    k_conv<<<4096, 256, 0, stream>>>(xr, conv_w, conv_b, xc);
    k_gemm<1><<<dim3(33, 32), 256, 0, stream>>>(xc, dt_w, x_projw + (size_t)64*2048,
                                                dtb, Bss, dt_b, nullptr, nullptr, nullptr, nullptr, 2048);
    // dtb [b*t][d] -> dtt [b][d][t];  xc [b*t][d] -> xct [b][d][t]
    k_tr<<<dim3(32, 16, 2), 256, 0, stream>>>(dtb, dtt, DI, L_DIM,
                                              (size_t)L_DIM*DI, (size_t)DI*L_DIM);
    k_tr<<<dim3(32, 16, 2), 256, 0, stream>>>(xc, xct, DI, L_DIM,
                                              (size_t)L_DIM*DI, (size_t)DI*L_DIM);
    k_scan2<<<1024, 256, 0, stream>>>(dtt, xct, Bss, A_log, D_param, yt);
    // yt [b][d][t] -> y [b*t][d]
    k_tr<<<dim3(16, 32, 2), 256, 0, stream>>>(yt, y, L_DIM, DI,
                                              (size_t)DI*L_DIM, (size_t)L_DIM*DI);
    k_gemm<2><<<dim3(16, 32), 256, 0, stream>>>(y, out_projw, nullptr, out, nullptr,
                                                nullptr, x, nullptr, nullptr, xr, 2048);
}

// Round 3
// 958.692 us; speedup vs baseline: 1.6066x; 1.3646x over previous
//
#include <hip/hip_runtime.h>
#include <hip/hip_bf16.h>
#include <math.h>

#define B_DIM 2
#define L_DIM 1024
#define DM 1024
#define DI 2048
#define NS 64

// ---------------- RMSNorm row factors (norm fused into GEMM0 staging) --------
__global__ __launch_bounds__(256) void k_rmsfac(const float* __restrict__ x,
                                                float* __restrict__ rinv)
{
    int row = blockIdx.x;
    float4 v = ((const float4*)(x + (size_t)row * DM))[threadIdx.x];
    float ss = v.x*v.x + v.y*v.y + v.z*v.z + v.w*v.w;
    #pragma unroll
    for (int m = 32; m; m >>= 1) ss += __shfl_xor(ss, m, 64);
    __shared__ float red[4];
    if ((threadIdx.x & 63) == 0) red[threadIdx.x >> 6] = ss;
    __syncthreads();
    if (threadIdx.x == 0) {
        float tot = red[0] + red[1] + red[2] + red[3];
        rinv[row] = rsqrtf(tot * (1.0f / DM) + 1e-6f);
    }
}

// ---------------- NT GEMM: C[m][n] = sum_k A[m][k] * Bw[n][k] ----------------
template<int MODE>
__global__ __launch_bounds__(256) void k_gemm(
    const float* __restrict__ A, const float* __restrict__ Bw0,
    const float* __restrict__ Bw1,
    float* __restrict__ C0, float* __restrict__ C1,
    const float* __restrict__ bias, const float* __restrict__ skip,
    const float* __restrict__ rinv, const float* __restrict__ normw,
    const float* __restrict__ gate, int Kdim)
{
    __shared__ float As[32][68];   // k-major
    __shared__ float Bs[32][68];
    const int t = threadIdx.x;
    const int nt = blockIdx.x, mt = blockIdx.y;
    const int mBase = mt * 64;
    const bool isXP = (MODE == 1) && (nt == 32);
    const float* __restrict__ Bw = isXP ? Bw1 : Bw0;
    const int nBaseB = isXP ? 0 : nt * 64;
    const int tx = t & 15, ty = t >> 4;
    float acc[4][4] = {};

    for (int kt = 0; kt < Kdim; kt += 32) {
        #pragma unroll
        for (int s = 0; s < 2; ++s) {
            int id = t + s * 256;
            int r = id >> 3, kq = id & 7;
            int kcol = kt + kq * 4;
            float4 va = *(const float4*)(A + (size_t)(mBase + r) * Kdim + kcol);
            if constexpr (MODE == 0) {
                float ri = rinv[mBase + r];
                float4 nw = *(const float4*)(normw + kcol);
                va.x *= ri * nw.x; va.y *= ri * nw.y;
                va.z *= ri * nw.z; va.w *= ri * nw.w;
            }
            if constexpr (MODE == 2) {
                float4 rv = *(const float4*)(gate + (size_t)(mBase + r) * (2*DI) + DI + kcol);
                va.x *= rv.x / (1.f + __expf(-rv.x));
                va.y *= rv.y / (1.f + __expf(-rv.y));
                va.z *= rv.z / (1.f + __expf(-rv.z));
                va.w *= rv.w / (1.f + __expf(-rv.w));
            }
            As[kq*4+0][r] = va.x; As[kq*4+1][r] = va.y;
            As[kq*4+2][r] = va.z; As[kq*4+3][r] = va.w;
            float4 vb = *(const float4*)(Bw + (size_t)(nBaseB + r) * Kdim + kcol);
            Bs[kq*4+0][r] = vb.x; Bs[kq*4+1][r] = vb.y;
            Bs[kq*4+2][r] = vb.z; Bs[kq*4+3][r] = vb.w;
        }
        __syncthreads();
        #pragma unroll
        for (int kk = 0; kk < 32; ++kk) {
            float4 a4 = *(const float4*)&As[kk][ty * 4];
            float4 b4 = *(const float4*)&Bs[kk][tx * 4];
            float av[4] = {a4.x, a4.y, a4.z, a4.w};
            float bv[4] = {b4.x, b4.y, b4.z, b4.w};
            #pragma unroll
            for (int i = 0; i < 4; ++i)
                #pragma unroll
                for (int j = 0; j < 4; ++j)
                    acc[i][j] = fmaf(av[i], bv[j], acc[i][j]);
        }
        __syncthreads();
    }

    const int col = (isXP ? 0 : nt * 64) + tx * 4;
    #pragma unroll
    for (int i = 0; i < 4; ++i) {
        int m = mBase + ty * 4 + i;
        if constexpr (MODE == 0) {
            float4 o = make_float4(acc[i][0], acc[i][1], acc[i][2], acc[i][3]);
            *(float4*)(C0 + (size_t)m * (2*DI) + col) = o;
        } else if constexpr (MODE == 1) {
            if (isXP) {
                float4 o = make_float4(acc[i][0], acc[i][1], acc[i][2], acc[i][3]);
                *(float4*)(C1 + (size_t)m * NS + col) = o;
            } else {
                float o[4];
                #pragma unroll
                for (int j = 0; j < 4; ++j) {
                    float z = acc[i][j] + bias[col + j];
                    o[j] = (z > 20.f) ? z : logf(1.f + expf(z));
                }
                float4 ov = make_float4(o[0], o[1], o[2], o[3]);
                *(float4*)(C0 + (size_t)m * DI + col) = ov;
            }
        } else {
            float4 sk = *(const float4*)(skip + (size_t)m * DM + col);
            float4 o = make_float4(acc[i][0] + sk.x, acc[i][1] + sk.y,
                                   acc[i][2] + sk.z, acc[i][3] + sk.w);
            *(float4*)(C0 + (size_t)m * DM + col) = o;
        }
    }
}

// ---------------- causal depthwise conv1d (K=4) + SiLU -----------------------
__global__ __launch_bounds__(256) void k_conv(const float* __restrict__ xr,
    const float* __restrict__ cw, const float* __restrict__ cb,
    float* __restrict__ xc)
{
    int gid = blockIdx.x * 256 + threadIdx.x;      // [0, 2*1024*512)
    int d = (gid & 511) * 4;
    int tt = (gid >> 9) & 1023;
    int b = gid >> 19;
    float4 w[4];
    #pragma unroll
    for (int c = 0; c < 4; ++c) w[c] = *(const float4*)(cw + (size_t)(d + c) * 4);
    float4 acc = *(const float4*)(cb + d);
    const float* base = xr + (size_t)b * L_DIM * (2*DI) + d;
    #pragma unroll
    for (int j = 0; j < 4; ++j) {
        int ti = tt - 3 + j;
        if (ti < 0) continue;
        float4 xv = *(const float4*)(base + (size_t)ti * (2*DI));
        const float* w0 = (const float*)&w[0];
        const float* w1 = (const float*)&w[1];
        const float* w2 = (const float*)&w[2];
        const float* w3 = (const float*)&w[3];
        acc.x = fmaf(w0[j], xv.x, acc.x);
        acc.y = fmaf(w1[j], xv.y, acc.y);
        acc.z = fmaf(w2[j], xv.z, acc.z);
        acc.w = fmaf(w3[j], xv.w, acc.w);
    }
    acc.x = acc.x / (1.f + expf(-acc.x));
    acc.y = acc.y / (1.f + expf(-acc.y));
    acc.z = acc.z / (1.f + expf(-acc.z));
    acc.w = acc.w / (1.f + expf(-acc.w));
    *(float4*)(xc + (size_t)(b * L_DIM + tt) * DI + d) = acc;
}

// ---------------- tiled transpose: dst[c][r] = src[r][c], batched ------------
__global__ __launch_bounds__(256) void k_tr(const float* __restrict__ src,
    float* __restrict__ dst, int srs, int drs, size_t sB, size_t dB)
{
    __shared__ float tile[64][65];
    const int r0 = blockIdx.y * 64, c0 = blockIdx.x * 64;
    const float* s = src + blockIdx.z * sB;
    float* d = dst + blockIdx.z * dB;
    const int tx = threadIdx.x & 15, ty = threadIdx.x >> 4;
    #pragma unroll
    for (int p = 0; p < 4; ++p) {
        float4 v = *(const float4*)(s + (size_t)(r0 + ty + p*16) * srs + c0 + tx*4);
        tile[ty + p*16][tx*4+0] = v.x; tile[ty + p*16][tx*4+1] = v.y;
        tile[ty + p*16][tx*4+2] = v.z; tile[ty + p*16][tx*4+3] = v.w;
    }
    __syncthreads();
    #pragma unroll
    for (int p = 0; p < 4; ++p) {
        int oc = ty + p*16;                       // local c index
        float4 v = make_float4(tile[tx*4+0][oc], tile[tx*4+1][oc],
                               tile[tx*4+2][oc], tile[tx*4+3][oc]);
        *(float4*)(d + (size_t)(c0 + oc) * drs + r0 + tx*4) = v;
    }
}

// ---------------- DPP wave-64 sum (result valid in lane 63), pure VALU -------
template<int CTRL, int RM>
__device__ __forceinline__ float dpp_add(float v)
{
    int x = __builtin_amdgcn_update_dpp(0, __float_as_int(v), CTRL, RM, 0xf, true);
    return v + __int_as_float(x);
}
__device__ __forceinline__ float wave_sum63(float v)
{
    v = dpp_add<0x111, 0xf>(v);   // row_shr:1
    v = dpp_add<0x112, 0xf>(v);   // row_shr:2
    v = dpp_add<0x114, 0xf>(v);   // row_shr:4
    v = dpp_add<0x118, 0xf>(v);   // row_shr:8 -> lane 15 of each row16 = row sum
    v = dpp_add<0x142, 0xa>(v);   // row_bcast:15 into rows 1,3
    v = dpp_add<0x143, 0xc>(v);   // row_bcast:31 into rows 2,3 -> lane 63 total
    return v;
}
__device__ __forceinline__ float rl(float v, int lane)
{
    return __int_as_float(__builtin_amdgcn_readlane(__float_as_int(v), lane));
}

// ---------------- selective scan v3: wave per (b,d), lane = state n ----------
// dtt, xct: [b][d][t]; Bss: [b][t][n]; output yt: [b][d][t] = h.sum + D*x
// Inner loop has exactly ONE DS op (Bs read); reduce + broadcasts are VALU.
__global__ __launch_bounds__(256) void k_scan3(const float* __restrict__ dtt,
    const float* __restrict__ xct, const float* __restrict__ Bss,
    const float* __restrict__ A_log, const float* __restrict__ Dp,
    float* __restrict__ yt)
{
    __shared__ float Bs[64][68];
    const int lane = threadIdx.x & 63;
    const int widx = threadIdx.x >> 6;
    const int b = blockIdx.x >> 9;
    const int d = (blockIdx.x & 511) * 4 + widx;
    const float aL2 = -expf(A_log[(size_t)d * NS + lane]) * 1.44269504f;
    const float Dv = Dp[d];
    const float* dtp = dtt + ((size_t)b * DI + d) * L_DIM;
    const float* xcp = xct + ((size_t)b * DI + d) * L_DIM;
    const float* Bp  = Bss + (size_t)b * L_DIM * NS;
    float* yp = yt + ((size_t)b * DI + d) * L_DIM;
    const int lr = threadIdx.x >> 2;          // 0..63: B row
    const int lc = (threadIdx.x & 3) * 16;    // B col base
    float h = 0.f;

    for (int t0 = 0; t0 < L_DIM; t0 += 64) {
        const float* bsrc = Bp + (size_t)(t0 + lr) * NS + lc;
        float4 b0 = *(const float4*)(bsrc);
        float4 b1 = *(const float4*)(bsrc + 4);
        float4 b2 = *(const float4*)(bsrc + 8);
        float4 b3 = *(const float4*)(bsrc + 12);
        float dt_v = dtp[t0 + lane];
        float xc_v = xcp[t0 + lane];
        __syncthreads();                       // prev chunk reads complete
        *(float4*)&Bs[lr][lc]      = b0;
        *(float4*)&Bs[lr][lc + 4]  = b1;
        *(float4*)&Bs[lr][lc + 8]  = b2;
        *(float4*)&Bs[lr][lc + 12] = b3;
        __syncthreads();
        float y_v = 0.f;
        #pragma unroll
        for (int tt = 0; tt < 64; ++tt) {
            float dts = rl(dt_v, tt);          // SGPR broadcast, no DS
            float xs  = rl(xc_v, tt);
            float ad = exp2f(aL2 * dts);
            float Bv = Bs[tt][lane];           // the one DS read
            h = fmaf(ad, h, xs * Bv);
            float s = wave_sum63(h);           // 6x v_add_f32_dpp
            float tot = rl(s, 63) + Dv * xs;
            y_v = (lane == tt) ? tot : y_v;    // v_cmp + cndmask
        }
        yp[t0 + lane] = y_v;
    }
}

extern "C" void kernel_launch(void* const* d_in, const int* in_sizes, int n_in,
                              void* d_out, int out_size, void* d_ws, size_t ws_size,
                              hipStream_t stream)
{
    const float* x        = (const float*)d_in[0];
    const float* norm_w   = (const float*)d_in[1];
    const float* in_projw = (const float*)d_in[2];
    const float* conv_w   = (const float*)d_in[3];
    const float* conv_b   = (const float*)d_in[4];
    const float* x_projw  = (const float*)d_in[5];
    const float* dt_w     = (const float*)d_in[6];
    const float* dt_b     = (const float*)d_in[7];
    const float* A_log    = (const float*)d_in[8];
    const float* D_param  = (const float*)d_in[9];
    const float* out_projw= (const float*)d_in[10];
    float* out = (float*)d_out;

    float* ws   = (float*)d_ws;
    float* rinv = ws;                               // 2048
    float* xr   = rinv + 2048;                      // 2048*4096
    float* xc   = xr  + (size_t)2048 * 4096;        // 2048*2048 (reused as y)
    float* dtb  = xc  + (size_t)2048 * 2048;        // 2048*2048 (reused as y_t)
    float* Bss  = dtb + (size_t)2048 * 2048;        // 2048*64
    float* dtt  = Bss + (size_t)2048 * 64;          // 2*2048*1024
    float* xct  = dtt + (size_t)2*2048*1024;        // 2*2048*1024
    float* yt   = dtb;                              // alias (dtb dead after transpose)
    float* y    = xc;                               // alias (xc dead after transposes)

    k_rmsfac<<<2048, 256, 0, stream>>>(x, rinv);
    k_gemm<0><<<dim3(64, 32), 256, 0, stream>>>(x, in_projw, nullptr, xr, nullptr,
                                                nullptr, nullptr, rinv, norm_w, nullptr, 1024);
    k_conv<<<4096, 256, 0, stream>>>(xr, conv_w, conv_b, xc);
    k_gemm<1><<<dim3(33, 32), 256, 0, stream>>>(xc, dt_w, x_projw + (size_t)64*2048,
                                                dtb, Bss, dt_b, nullptr, nullptr, nullptr, nullptr, 2048);
    // dtb [b*t][d] -> dtt [b][d][t];  xc [b*t][d] -> xct [b][d][t]
    k_tr<<<dim3(32, 16, 2), 256, 0, stream>>>(dtb, dtt, DI, L_DIM,
                                              (size_t)L_DIM*DI, (size_t)DI*L_DIM);
    k_tr<<<dim3(32, 16, 2), 256, 0, stream>>>(xc, xct, DI, L_DIM,
                                              (size_t)L_DIM*DI, (size_t)DI*L_DIM);
    k_scan3<<<1024, 256, 0, stream>>>(dtt, xct, Bss, A_log, D_param, yt);
    // yt [b][d][t] -> y [b*t][d]
    k_tr<<<dim3(16, 32, 2), 256, 0, stream>>>(yt, y, L_DIM, DI,
                                              (size_t)DI*L_DIM, (size_t)L_DIM*DI);
    k_gemm<2><<<dim3(16, 32), 256, 0, stream>>>(y, out_projw, nullptr, out, nullptr,
                                                nullptr, x, nullptr, nullptr, xr, 2048);
}

// Round 4
// 409.923 us; speedup vs baseline: 3.7574x; 2.3387x over previous
//
#include <hip/hip_runtime.h>
#include <hip/hip_bf16.h>
#include <math.h>

#define L_DIM 1024
#define DM 1024
#define DI 2048
#define NS 64

typedef __attribute__((ext_vector_type(8))) short short8;
typedef __attribute__((ext_vector_type(4))) float f32x4;

// round-to-nearest-even f32 -> bf16 bits
__device__ __forceinline__ ushort bf16u(float f)
{
    unsigned u = __float_as_uint(f);
    unsigned r = (u + 0x7fffu + ((u >> 16) & 1u)) >> 16;
    return (ushort)r;
}

__device__ __forceinline__ void gld16(const ushort* g, const ushort* l)
{
    __builtin_amdgcn_global_load_lds(
        (const __attribute__((address_space(1))) unsigned int*)g,
        (__attribute__((address_space(3))) unsigned int*)l, 16, 0, 0);
}

// ---------------- RMSNorm row factors ----------------------------------------
__global__ __launch_bounds__(256) void k_rmsfac(const float* __restrict__ x,
                                                float* __restrict__ rinv)
{
    int row = blockIdx.x;
    float4 v = ((const float4*)(x + (size_t)row * DM))[threadIdx.x];
    float ss = v.x*v.x + v.y*v.y + v.z*v.z + v.w*v.w;
    #pragma unroll
    for (int m = 32; m; m >>= 1) ss += __shfl_xor(ss, m, 64);
    __shared__ float red[4];
    if ((threadIdx.x & 63) == 0) red[threadIdx.x >> 6] = ss;
    __syncthreads();
    if (threadIdx.x == 0) {
        float tot = red[0] + red[1] + red[2] + red[3];
        rinv[row] = rsqrtf(tot * (1.0f / DM) + 1e-6f);
    }
}

// ---------------- generic f32 -> bf16 cast (8 elems/thread) ------------------
__global__ __launch_bounds__(256) void k_cast(const float* __restrict__ s,
                                              ushort* __restrict__ d, int n8)
{
    int i = blockIdx.x * 256 + threadIdx.x;
    if (i >= n8) return;
    float4 a = ((const float4*)s)[2*i], b = ((const float4*)s)[2*i+1];
    ((ushort4*)d)[2*i]   = make_ushort4(bf16u(a.x), bf16u(a.y), bf16u(a.z), bf16u(a.w));
    ((ushort4*)d)[2*i+1] = make_ushort4(bf16u(b.x), bf16u(b.y), bf16u(b.z), bf16u(b.w));
}

// ---------------- xn = bf16(x * rinv[row] * norm_w[k])  [2048][1024] ---------
__global__ __launch_bounds__(256) void k_cast_xn(const float* __restrict__ x,
    const float* __restrict__ rinv, const float* __restrict__ nw,
    ushort* __restrict__ d)
{
    int i = blockIdx.x * 256 + threadIdx.x;      // 262144 total
    int row = i >> 7, cb = (i & 127) * 8;
    float ri = rinv[row];
    const float* xp = x + (size_t)row * DM + cb;
    float4 a = *(const float4*)xp, b = *(const float4*)(xp + 4);
    float4 wa = *(const float4*)(nw + cb), wb = *(const float4*)(nw + cb + 4);
    ushort* dp = d + (size_t)row * DM + cb;
    *(ushort4*)dp = make_ushort4(bf16u(a.x*ri*wa.x), bf16u(a.y*ri*wa.y),
                                 bf16u(a.z*ri*wa.z), bf16u(a.w*ri*wa.w));
    *(ushort4*)(dp+4) = make_ushort4(bf16u(b.x*ri*wb.x), bf16u(b.y*ri*wb.y),
                                     bf16u(b.z*ri*wb.z), bf16u(b.w*ri*wb.w));
}

// ---------------- MFMA NT GEMM: C[m][n] = sum_k A[m][k]*Bw[n][k] -------------
// 128x128 tile, BK=32, 4 waves (2x2), each wave 64x64 via 4x4 16x16x32 frags.
// MODE 0: C0=xr f32 (ldc=4096)
// MODE 1: nt<16: C0 = dt = softplus(acc+bias) (ldc=2048); nt==16: C1 = Bss [.][64]
// MODE 2: C0 = acc + skip (ldc=1024)
template<int MODE>
__global__ __launch_bounds__(256) void k_mfma(
    const ushort* __restrict__ Abf, const ushort* __restrict__ Bbf0,
    const ushort* __restrict__ Bbf1, float* __restrict__ C0,
    float* __restrict__ C1, const float* __restrict__ bias,
    const float* __restrict__ skip, int Kdim, int ldc)
{
    __shared__ __align__(16) ushort As[128*32];
    __shared__ __align__(16) ushort Bs[128*32];
    const int t = threadIdx.x, w = t >> 6, lane = t & 63;
    const int nt = blockIdx.x, mt = blockIdx.y;
    const int mBase = mt * 128, nBase = nt * 128;
    const bool isXP = (MODE == 1) && (nt == 16);
    const ushort* __restrict__ Bbf = isXP ? Bbf1 : Bbf0;
    const int wr = (w >> 1) * 64, wc = (w & 1) * 64;
    const int sR = lane >> 2, sK = (lane & 3) * 8;

    f32x4 acc[4][4];
    #pragma unroll
    for (int i = 0; i < 4; ++i)
        #pragma unroll
        for (int j = 0; j < 4; ++j)
            acc[i][j] = (f32x4){0.f, 0.f, 0.f, 0.f};

    for (int kt = 0; kt < Kdim; kt += 32) {
        #pragma unroll
        for (int s = 0; s < 2; ++s) {
            int tr = w*32 + s*16 + sR;
            gld16(Abf + (size_t)(mBase + tr) * Kdim + kt + sK,
                  As + (w*32 + s*16) * 32);
            int gr = isXP ? (tr < 63 ? tr : 63) : (nBase + tr);
            gld16(Bbf + (size_t)gr * Kdim + kt + sK,
                  Bs + (w*32 + s*16) * 32);
        }
        __syncthreads();                 // drains vmcnt -> LDS tiles ready
        short8 af[4], bfr[4];
        #pragma unroll
        for (int f = 0; f < 4; ++f) {
            af[f]  = *(const short8*)(As + (wr + f*16 + (lane & 15))*32 + (lane >> 4)*8);
            bfr[f] = *(const short8*)(Bs + (wc + f*16 + (lane & 15))*32 + (lane >> 4)*8);
        }
        #pragma unroll
        for (int mi = 0; mi < 4; ++mi)
            #pragma unroll
            for (int ni = 0; ni < 4; ++ni)
                acc[mi][ni] = __builtin_amdgcn_mfma_f32_16x16x32_bf16(
                    af[mi], bfr[ni], acc[mi][ni], 0, 0, 0);
        __syncthreads();                 // protect LDS before next staging
    }

    const int rb = (lane >> 4) * 4, cbl = lane & 15;
    #pragma unroll
    for (int mi = 0; mi < 4; ++mi) {
        #pragma unroll
        for (int ni = 0; ni < 4; ++ni) {
            int ltcol = wc + ni*16 + cbl;
            int col = nBase + ltcol;
            #pragma unroll
            for (int j = 0; j < 4; ++j) {
                int row = mBase + wr + mi*16 + rb + j;
                float v = acc[mi][ni][j];
                if constexpr (MODE == 0) {
                    C0[(size_t)row * ldc + col] = v;
                } else if constexpr (MODE == 1) {
                    if (isXP) {
                        if (ltcol < NS) C1[(size_t)row * NS + ltcol] = v;
                    } else {
                        float z = v + bias[col];
                        C0[(size_t)row * ldc + col] =
                            (z > 20.f) ? z : logf(1.f + expf(z));
                    }
                } else {
                    C0[(size_t)row * ldc + col] = v + skip[(size_t)row * ldc + col];
                }
            }
        }
    }
}

// ---------------- causal depthwise conv1d (K=4) + SiLU, f32 + bf16 out -------
__global__ __launch_bounds__(256) void k_conv(const float* __restrict__ xr,
    const float* __restrict__ cw, const float* __restrict__ cb,
    float* __restrict__ xc, ushort* __restrict__ xcb)
{
    int gid = blockIdx.x * 256 + threadIdx.x;      // [0, 2*1024*512)
    int d = (gid & 511) * 4;
    int tt = (gid >> 9) & 1023;
    int b = gid >> 19;
    float4 w[4];
    #pragma unroll
    for (int c = 0; c < 4; ++c) w[c] = *(const float4*)(cw + (size_t)(d + c) * 4);
    float4 acc = *(const float4*)(cb + d);
    const float* base = xr + (size_t)b * L_DIM * (2*DI) + d;
    #pragma unroll
    for (int j = 0; j < 4; ++j) {
        int ti = tt - 3 + j;
        if (ti < 0) continue;
        float4 xv = *(const float4*)(base + (size_t)ti * (2*DI));
        const float* w0 = (const float*)&w[0];
        const float* w1 = (const float*)&w[1];
        const float* w2 = (const float*)&w[2];
        const float* w3 = (const float*)&w[3];
        acc.x = fmaf(w0[j], xv.x, acc.x);
        acc.y = fmaf(w1[j], xv.y, acc.y);
        acc.z = fmaf(w2[j], xv.z, acc.z);
        acc.w = fmaf(w3[j], xv.w, acc.w);
    }
    acc.x = acc.x / (1.f + expf(-acc.x));
    acc.y = acc.y / (1.f + expf(-acc.y));
    acc.z = acc.z / (1.f + expf(-acc.z));
    acc.w = acc.w / (1.f + expf(-acc.w));
    size_t o = (size_t)(b * L_DIM + tt) * DI + d;
    *(float4*)(xc + o) = acc;
    *(ushort4*)(xcb + o) = make_ushort4(bf16u(acc.x), bf16u(acc.y),
                                        bf16u(acc.z), bf16u(acc.w));
}

// ---------------- tiled transpose: dst[c][r] = src[r][c], batched ------------
__global__ __launch_bounds__(256) void k_tr(const float* __restrict__ src,
    float* __restrict__ dst, int srs, int drs, size_t sB, size_t dB)
{
    __shared__ float tile[64][65];
    const int r0 = blockIdx.y * 64, c0 = blockIdx.x * 64;
    const float* s = src + blockIdx.z * sB;
    float* d = dst + blockIdx.z * dB;
    const int tx = threadIdx.x & 15, ty = threadIdx.x >> 4;
    #pragma unroll
    for (int p = 0; p < 4; ++p) {
        float4 v = *(const float4*)(s + (size_t)(r0 + ty + p*16) * srs + c0 + tx*4);
        tile[ty + p*16][tx*4+0] = v.x; tile[ty + p*16][tx*4+1] = v.y;
        tile[ty + p*16][tx*4+2] = v.z; tile[ty + p*16][tx*4+3] = v.w;
    }
    __syncthreads();
    #pragma unroll
    for (int p = 0; p < 4; ++p) {
        int oc = ty + p*16;
        float4 v = make_float4(tile[tx*4+0][oc], tile[tx*4+1][oc],
                               tile[tx*4+2][oc], tile[tx*4+3][oc]);
        *(float4*)(d + (size_t)(c0 + oc) * drs + r0 + tx*4) = v;
    }
}

// ------ back-transpose yt[b][d][t] -> y_bf[b*t][d], fused silu(res) gate -----
__global__ __launch_bounds__(256) void k_trg(const float* __restrict__ yt,
    const float* __restrict__ xr, ushort* __restrict__ ybf)
{
    __shared__ float tile[64][65];
    const int r0 = blockIdx.y * 64, c0 = blockIdx.x * 64;   // r=d, c=t
    const int z = blockIdx.z;
    const float* s = yt + (size_t)z * DI * L_DIM;
    const int tx = threadIdx.x & 15, ty = threadIdx.x >> 4;
    #pragma unroll
    for (int p = 0; p < 4; ++p) {
        float4 v = *(const float4*)(s + (size_t)(r0 + ty + p*16) * L_DIM + c0 + tx*4);
        tile[ty + p*16][tx*4+0] = v.x; tile[ty + p*16][tx*4+1] = v.y;
        tile[ty + p*16][tx*4+2] = v.z; tile[ty + p*16][tx*4+3] = v.w;
    }
    __syncthreads();
    #pragma unroll
    for (int p = 0; p < 4; ++p) {
        int oc = ty + p*16;                       // local t index
        int row = z * L_DIM + c0 + oc;            // global (b*t) row
        float4 v = make_float4(tile[tx*4+0][oc], tile[tx*4+1][oc],
                               tile[tx*4+2][oc], tile[tx*4+3][oc]);
        float4 g = *(const float4*)(xr + (size_t)row * (2*DI) + DI + r0 + tx*4);
        v.x *= g.x / (1.f + expf(-g.x));
        v.y *= g.y / (1.f + expf(-g.y));
        v.z *= g.z / (1.f + expf(-g.z));
        v.w *= g.w / (1.f + expf(-g.w));
        *(ushort4*)(ybf + (size_t)row * DI + r0 + tx*4) =
            make_ushort4(bf16u(v.x), bf16u(v.y), bf16u(v.z), bf16u(v.w));
    }
}

// ---------------- DPP wave-64 sum + readlane helpers -------------------------
template<int CTRL, int RM>
__device__ __forceinline__ float dpp_add(float v)
{
    int x = __builtin_amdgcn_update_dpp(0, __float_as_int(v), CTRL, RM, 0xf, true);
    return v + __int_as_float(x);
}
__device__ __forceinline__ float wave_sum63(float v)
{
    v = dpp_add<0x111, 0xf>(v);
    v = dpp_add<0x112, 0xf>(v);
    v = dpp_add<0x114, 0xf>(v);
    v = dpp_add<0x118, 0xf>(v);
    v = dpp_add<0x142, 0xa>(v);
    v = dpp_add<0x143, 0xc>(v);
    return v;
}
__device__ __forceinline__ float rl(float v, int lane)
{
    return __int_as_float(__builtin_amdgcn_readlane(__float_as_int(v), lane));
}

// ---------------- selective scan v3 ------------------------------------------
__global__ __launch_bounds__(256) void k_scan3(const float* __restrict__ dtt,
    const float* __restrict__ xct, const float* __restrict__ Bss,
    const float* __restrict__ A_log, const float* __restrict__ Dp,
    float* __restrict__ yt)
{
    __shared__ float Bsh[64][68];
    const int lane = threadIdx.x & 63;
    const int widx = threadIdx.x >> 6;
    const int b = blockIdx.x >> 9;
    const int d = (blockIdx.x & 511) * 4 + widx;
    const float aL2 = -expf(A_log[(size_t)d * NS + lane]) * 1.44269504f;
    const float Dv = Dp[d];
    const float* dtp = dtt + ((size_t)b * DI + d) * L_DIM;
    const float* xcp = xct + ((size_t)b * DI + d) * L_DIM;
    const float* Bp  = Bss + (size_t)b * L_DIM * NS;
    float* yp = yt + ((size_t)b * DI + d) * L_DIM;
    const int lr = threadIdx.x >> 2;
    const int lc = (threadIdx.x & 3) * 16;
    float h = 0.f;

    for (int t0 = 0; t0 < L_DIM; t0 += 64) {
        const float* bsrc = Bp + (size_t)(t0 + lr) * NS + lc;
        float4 b0 = *(const float4*)(bsrc);
        float4 b1 = *(const float4*)(bsrc + 4);
        float4 b2 = *(const float4*)(bsrc + 8);
        float4 b3 = *(const float4*)(bsrc + 12);
        float dt_v = dtp[t0 + lane];
        float xc_v = xcp[t0 + lane];
        __syncthreads();
        *(float4*)&Bsh[lr][lc]      = b0;
        *(float4*)&Bsh[lr][lc + 4]  = b1;
        *(float4*)&Bsh[lr][lc + 8]  = b2;
        *(float4*)&Bsh[lr][lc + 12] = b3;
        __syncthreads();
        float y_v = 0.f;
        #pragma unroll
        for (int tt = 0; tt < 64; ++tt) {
            float dts = rl(dt_v, tt);
            float xs  = rl(xc_v, tt);
            float ad = exp2f(aL2 * dts);
            float Bv = Bsh[tt][lane];
            h = fmaf(ad, h, xs * Bv);
            float s = wave_sum63(h);
            float tot = rl(s, 63) + Dv * xs;
            y_v = (lane == tt) ? tot : y_v;
        }
        yp[t0 + lane] = y_v;
    }
}

extern "C" void kernel_launch(void* const* d_in, const int* in_sizes, int n_in,
                              void* d_out, int out_size, void* d_ws, size_t ws_size,
                              hipStream_t stream)
{
    const float* x        = (const float*)d_in[0];
    const float* norm_w   = (const float*)d_in[1];
    const float* in_projw = (const float*)d_in[2];
    const float* conv_w   = (const float*)d_in[3];
    const float* conv_b   = (const float*)d_in[4];
    const float* x_projw  = (const float*)d_in[5];
    const float* dt_w     = (const float*)d_in[6];
    const float* dt_b     = (const float*)d_in[7];
    const float* A_log    = (const float*)d_in[8];
    const float* D_param  = (const float*)d_in[9];
    const float* out_projw= (const float*)d_in[10];
    float* out = (float*)d_out;

    float* ws   = (float*)d_ws;
    float* rinv = ws;                               // 4096 (pad)
    float* xr   = rinv + 4096;                      // 8M f32
    float* xc   = xr + (size_t)8*1024*1024;         // 4M f32
    float* dtb  = xc + (size_t)4*1024*1024;         // 4M f32 (yt alias)
    float* Bss  = dtb + (size_t)4*1024*1024;        // 128K f32
    float* dtt  = Bss + 131072;                     // 4M f32
    float* xct  = dtt + (size_t)4*1024*1024;        // 4M f32
    ushort* xn_bf  = (ushort*)(xct + (size_t)4*1024*1024); // 2M u16
    ushort* xc_bf  = xn_bf + (size_t)2*1024*1024;          // 4M u16
    ushort* xpw_bf = xc_bf + (size_t)4*1024*1024;          // 128K u16
    // aliases into dead regions:
    ushort* inpw_bf = (ushort*)dtt;   // 4M u16; dead before dtt written
    ushort* dtw_bf  = (ushort*)xct;   // 4M u16; dead before xct written
    ushort* opw_bf  = xn_bf;          // 2M u16; xn dead after GEMM0
    ushort* y_bf    = (ushort*)xc;    // 4M u16; xc dead after transpose
    float* yt = dtb;

    k_rmsfac<<<2048, 256, 0, stream>>>(x, rinv);
    k_cast_xn<<<1024, 256, 0, stream>>>(x, rinv, norm_w, xn_bf);
    k_cast<<<2048, 256, 0, stream>>>(in_projw, inpw_bf, 524288);
    // GEMM0: xr = xn @ in_proj^T   [2048][4096], K=1024
    k_mfma<0><<<dim3(32, 16), 256, 0, stream>>>(xn_bf, inpw_bf, nullptr,
                                                xr, nullptr, nullptr, nullptr, 1024, 4096);
    k_conv<<<4096, 256, 0, stream>>>(xr, conv_w, conv_b, xc, xc_bf);
    k_cast<<<2048, 256, 0, stream>>>(dt_w, dtw_bf, 524288);
    k_cast<<<64, 256, 0, stream>>>(x_projw + (size_t)64*2048, xpw_bf, 16384);
    // GEMM1: dt = softplus(xc @ dt_w^T + b) [2048][2048]; Bss = xc @ xp^T [2048][64]
    k_mfma<1><<<dim3(17, 16), 256, 0, stream>>>(xc_bf, dtw_bf, xpw_bf,
                                                dtb, Bss, dt_b, nullptr, 2048, 2048);
    k_tr<<<dim3(32, 16, 2), 256, 0, stream>>>(dtb, dtt, DI, L_DIM,
                                              (size_t)L_DIM*DI, (size_t)DI*L_DIM);
    k_tr<<<dim3(32, 16, 2), 256, 0, stream>>>(xc, xct, DI, L_DIM,
                                              (size_t)L_DIM*DI, (size_t)DI*L_DIM);
    k_scan3<<<1024, 256, 0, stream>>>(dtt, xct, Bss, A_log, D_param, yt);
    k_cast<<<1024, 256, 0, stream>>>(out_projw, opw_bf, 262144);
    k_trg<<<dim3(16, 32, 2), 256, 0, stream>>>(yt, xr, y_bf);
    // GEMM2: out = (y*silu(res)) @ out_proj^T + skip  [2048][1024], K=2048
    k_mfma<2><<<dim3(8, 16), 256, 0, stream>>>(y_bf, opw_bf, nullptr,
                                               out, nullptr, nullptr, x, 2048, 1024);
}

// Round 5
// 409.789 us; speedup vs baseline: 3.7586x; 1.0003x over previous
//
#include <hip/hip_runtime.h>
#include <hip/hip_bf16.h>
#include <math.h>

#define L_DIM 1024
#define DM 1024
#define DI 2048
#define NS 64

typedef __attribute__((ext_vector_type(8))) short short8;
typedef __attribute__((ext_vector_type(4))) float f32x4;

// round-to-nearest-even f32 -> bf16 bits
__device__ __forceinline__ ushort bf16u(float f)
{
    unsigned u = __float_as_uint(f);
    unsigned r = (u + 0x7fffu + ((u >> 16) & 1u)) >> 16;
    return (ushort)r;
}

__device__ __forceinline__ void gld16(const ushort* g, const ushort* l)
{
    __builtin_amdgcn_global_load_lds(
        (const __attribute__((address_space(1))) unsigned int*)g,
        (__attribute__((address_space(3))) unsigned int*)l, 16, 0, 0);
}

// ---------------- RMSNorm row factors ----------------------------------------
__global__ __launch_bounds__(256) void k_rmsfac(const float* __restrict__ x,
                                                float* __restrict__ rinv)
{
    int row = blockIdx.x;
    float4 v = ((const float4*)(x + (size_t)row * DM))[threadIdx.x];
    float ss = v.x*v.x + v.y*v.y + v.z*v.z + v.w*v.w;
    #pragma unroll
    for (int m = 32; m; m >>= 1) ss += __shfl_xor(ss, m, 64);
    __shared__ float red[4];
    if ((threadIdx.x & 63) == 0) red[threadIdx.x >> 6] = ss;
    __syncthreads();
    if (threadIdx.x == 0) {
        float tot = red[0] + red[1] + red[2] + red[3];
        rinv[row] = rsqrtf(tot * (1.0f / DM) + 1e-6f);
    }
}

// ---------------- generic f32 -> bf16 cast (8 elems/thread) ------------------
__global__ __launch_bounds__(256) void k_cast(const float* __restrict__ s,
                                              ushort* __restrict__ d, int n8)
{
    int i = blockIdx.x * 256 + threadIdx.x;
    if (i >= n8) return;
    float4 a = ((const float4*)s)[2*i], b = ((const float4*)s)[2*i+1];
    ((ushort4*)d)[2*i]   = make_ushort4(bf16u(a.x), bf16u(a.y), bf16u(a.z), bf16u(a.w));
    ((ushort4*)d)[2*i+1] = make_ushort4(bf16u(b.x), bf16u(b.y), bf16u(b.z), bf16u(b.w));
}

// ---------------- xn = bf16(x * rinv[row] * norm_w[k])  [2048][1024] ---------
__global__ __launch_bounds__(256) void k_cast_xn(const float* __restrict__ x,
    const float* __restrict__ rinv, const float* __restrict__ nw,
    ushort* __restrict__ d)
{
    int i = blockIdx.x * 256 + threadIdx.x;      // 262144 total
    int row = i >> 7, cb = (i & 127) * 8;
    float ri = rinv[row];
    const float* xp = x + (size_t)row * DM + cb;
    float4 a = *(const float4*)xp, b = *(const float4*)(xp + 4);
    float4 wa = *(const float4*)(nw + cb), wb = *(const float4*)(nw + cb + 4);
    ushort* dp = d + (size_t)row * DM + cb;
    *(ushort4*)dp = make_ushort4(bf16u(a.x*ri*wa.x), bf16u(a.y*ri*wa.y),
                                 bf16u(a.z*ri*wa.z), bf16u(a.w*ri*wa.w));
    *(ushort4*)(dp+4) = make_ushort4(bf16u(b.x*ri*wb.x), bf16u(b.y*ri*wb.y),
                                     bf16u(b.z*ri*wb.z), bf16u(b.w*ri*wb.w));
}

// ---------------- MFMA NT GEMM: C[m][n] = sum_k A[m][k]*Bw[n][k] -------------
template<int MODE>
__global__ __launch_bounds__(256) void k_mfma(
    const ushort* __restrict__ Abf, const ushort* __restrict__ Bbf0,
    const ushort* __restrict__ Bbf1, float* __restrict__ C0,
    float* __restrict__ C1, const float* __restrict__ bias,
    const float* __restrict__ skip, int Kdim, int ldc)
{
    __shared__ __align__(16) ushort As[128*32];
    __shared__ __align__(16) ushort Bs[128*32];
    const int t = threadIdx.x, w = t >> 6, lane = t & 63;
    const int nt = blockIdx.x, mt = blockIdx.y;
    const int mBase = mt * 128, nBase = nt * 128;
    const bool isXP = (MODE == 1) && (nt == 16);
    const ushort* __restrict__ Bbf = isXP ? Bbf1 : Bbf0;
    const int wr = (w >> 1) * 64, wc = (w & 1) * 64;
    const int sR = lane >> 2, sK = (lane & 3) * 8;

    f32x4 acc[4][4];
    #pragma unroll
    for (int i = 0; i < 4; ++i)
        #pragma unroll
        for (int j = 0; j < 4; ++j)
            acc[i][j] = (f32x4){0.f, 0.f, 0.f, 0.f};

    for (int kt = 0; kt < Kdim; kt += 32) {
        #pragma unroll
        for (int s = 0; s < 2; ++s) {
            int tr = w*32 + s*16 + sR;
            gld16(Abf + (size_t)(mBase + tr) * Kdim + kt + sK,
                  As + (w*32 + s*16) * 32);
            int gr = isXP ? (tr < 63 ? tr : 63) : (nBase + tr);
            gld16(Bbf + (size_t)gr * Kdim + kt + sK,
                  Bs + (w*32 + s*16) * 32);
        }
        __syncthreads();
        short8 af[4], bfr[4];
        #pragma unroll
        for (int f = 0; f < 4; ++f) {
            af[f]  = *(const short8*)(As + (wr + f*16 + (lane & 15))*32 + (lane >> 4)*8);
            bfr[f] = *(const short8*)(Bs + (wc + f*16 + (lane & 15))*32 + (lane >> 4)*8);
        }
        #pragma unroll
        for (int mi = 0; mi < 4; ++mi)
            #pragma unroll
            for (int ni = 0; ni < 4; ++ni)
                acc[mi][ni] = __builtin_amdgcn_mfma_f32_16x16x32_bf16(
                    af[mi], bfr[ni], acc[mi][ni], 0, 0, 0);
        __syncthreads();
    }

    const int rb = (lane >> 4) * 4, cbl = lane & 15;
    #pragma unroll
    for (int mi = 0; mi < 4; ++mi) {
        #pragma unroll
        for (int ni = 0; ni < 4; ++ni) {
            int ltcol = wc + ni*16 + cbl;
            int col = nBase + ltcol;
            #pragma unroll
            for (int j = 0; j < 4; ++j) {
                int row = mBase + wr + mi*16 + rb + j;
                float v = acc[mi][ni][j];
                if constexpr (MODE == 0) {
                    C0[(size_t)row * ldc + col] = v;
                } else if constexpr (MODE == 1) {
                    if (isXP) {
                        if (ltcol < NS) C1[(size_t)row * NS + ltcol] = v;
                    } else {
                        float z = v + bias[col];
                        C0[(size_t)row * ldc + col] =
                            (z > 20.f) ? z : logf(1.f + expf(z));
                    }
                } else {
                    C0[(size_t)row * ldc + col] = v + skip[(size_t)row * ldc + col];
                }
            }
        }
    }
}

// ---------------- causal depthwise conv1d (K=4) + SiLU, f32 + bf16 out -------
__global__ __launch_bounds__(256) void k_conv(const float* __restrict__ xr,
    const float* __restrict__ cw, const float* __restrict__ cb,
    float* __restrict__ xc, ushort* __restrict__ xcb)
{
    int gid = blockIdx.x * 256 + threadIdx.x;      // [0, 2*1024*512)
    int d = (gid & 511) * 4;
    int tt = (gid >> 9) & 1023;
    int b = gid >> 19;
    float4 w[4];
    #pragma unroll
    for (int c = 0; c < 4; ++c) w[c] = *(const float4*)(cw + (size_t)(d + c) * 4);
    float4 acc = *(const float4*)(cb + d);
    const float* base = xr + (size_t)b * L_DIM * (2*DI) + d;
    #pragma unroll
    for (int j = 0; j < 4; ++j) {
        int ti = tt - 3 + j;
        if (ti < 0) continue;
        float4 xv = *(const float4*)(base + (size_t)ti * (2*DI));
        const float* w0 = (const float*)&w[0];
        const float* w1 = (const float*)&w[1];
        const float* w2 = (const float*)&w[2];
        const float* w3 = (const float*)&w[3];
        acc.x = fmaf(w0[j], xv.x, acc.x);
        acc.y = fmaf(w1[j], xv.y, acc.y);
        acc.z = fmaf(w2[j], xv.z, acc.z);
        acc.w = fmaf(w3[j], xv.w, acc.w);
    }
    acc.x = acc.x / (1.f + expf(-acc.x));
    acc.y = acc.y / (1.f + expf(-acc.y));
    acc.z = acc.z / (1.f + expf(-acc.z));
    acc.w = acc.w / (1.f + expf(-acc.w));
    size_t o = (size_t)(b * L_DIM + tt) * DI + d;
    *(float4*)(xc + o) = acc;
    *(ushort4*)(xcb + o) = make_ushort4(bf16u(acc.x), bf16u(acc.y),
                                        bf16u(acc.z), bf16u(acc.w));
}

// ---------------- tiled transpose: dst[c][r] = src[r][c], batched ------------
__global__ __launch_bounds__(256) void k_tr(const float* __restrict__ src,
    float* __restrict__ dst, int srs, int drs, size_t sB, size_t dB)
{
    __shared__ float tile[64][65];
    const int r0 = blockIdx.y * 64, c0 = blockIdx.x * 64;
    const float* s = src + blockIdx.z * sB;
    float* d = dst + blockIdx.z * dB;
    const int tx = threadIdx.x & 15, ty = threadIdx.x >> 4;
    #pragma unroll
    for (int p = 0; p < 4; ++p) {
        float4 v = *(const float4*)(s + (size_t)(r0 + ty + p*16) * srs + c0 + tx*4);
        tile[ty + p*16][tx*4+0] = v.x; tile[ty + p*16][tx*4+1] = v.y;
        tile[ty + p*16][tx*4+2] = v.z; tile[ty + p*16][tx*4+3] = v.w;
    }
    __syncthreads();
    #pragma unroll
    for (int p = 0; p < 4; ++p) {
        int oc = ty + p*16;
        float4 v = make_float4(tile[tx*4+0][oc], tile[tx*4+1][oc],
                               tile[tx*4+2][oc], tile[tx*4+3][oc]);
        *(float4*)(d + (size_t)(c0 + oc) * drs + r0 + tx*4) = v;
    }
}

// ------ back-transpose yt[b][d][t] -> y_bf[b*t][d], fused silu(res) gate -----
__global__ __launch_bounds__(256) void k_trg(const float* __restrict__ yt,
    const float* __restrict__ xr, ushort* __restrict__ ybf)
{
    __shared__ float tile[64][65];
    const int r0 = blockIdx.y * 64, c0 = blockIdx.x * 64;   // r=d, c=t
    const int z = blockIdx.z;
    const float* s = yt + (size_t)z * DI * L_DIM;
    const int tx = threadIdx.x & 15, ty = threadIdx.x >> 4;
    #pragma unroll
    for (int p = 0; p < 4; ++p) {
        float4 v = *(const float4*)(s + (size_t)(r0 + ty + p*16) * L_DIM + c0 + tx*4);
        tile[ty + p*16][tx*4+0] = v.x; tile[ty + p*16][tx*4+1] = v.y;
        tile[ty + p*16][tx*4+2] = v.z; tile[ty + p*16][tx*4+3] = v.w;
    }
    __syncthreads();
    #pragma unroll
    for (int p = 0; p < 4; ++p) {
        int oc = ty + p*16;                       // local t index
        int row = z * L_DIM + c0 + oc;            // global (b*t) row
        float4 v = make_float4(tile[tx*4+0][oc], tile[tx*4+1][oc],
                               tile[tx*4+2][oc], tile[tx*4+3][oc]);
        float4 g = *(const float4*)(xr + (size_t)row * (2*DI) + DI + r0 + tx*4);
        v.x *= g.x / (1.f + expf(-g.x));
        v.y *= g.y / (1.f + expf(-g.y));
        v.z *= g.z / (1.f + expf(-g.z));
        v.w *= g.w / (1.f + expf(-g.w));
        *(ushort4*)(ybf + (size_t)row * DI + r0 + tx*4) =
            make_ushort4(bf16u(v.x), bf16u(v.y), bf16u(v.z), bf16u(v.w));
    }
}

// ---------------- DPP helpers ------------------------------------------------
template<int CTRL, int RM>
__device__ __forceinline__ float dpp_add(float v)
{
    int x = __builtin_amdgcn_update_dpp(0, __float_as_int(v), CTRL, RM, 0xf, true);
    return v + __int_as_float(x);
}
// one stage of the wave-64 sum applied to 4 independent values (fills hazards)
template<int CTRL, int RM>
__device__ __forceinline__ void dpp_add4(float& a, float& b, float& c, float& d)
{
    a = dpp_add<CTRL, RM>(a);
    b = dpp_add<CTRL, RM>(b);
    c = dpp_add<CTRL, RM>(c);
    d = dpp_add<CTRL, RM>(d);
}
__device__ __forceinline__ float rl(float v, int lane)
{
    return __int_as_float(__builtin_amdgcn_readlane(__float_as_int(v), lane));
}

// ---------------- selective scan v4: 4-step batched DPP reduce ---------------
// dtt, xct: [b][d][t]; Bss: [b][t][n]; yt: [b][d][t] = h.sum + D*x
__global__ __launch_bounds__(256) void k_scan4(const float* __restrict__ dtt,
    const float* __restrict__ xct, const float* __restrict__ Bss,
    const float* __restrict__ A_log, const float* __restrict__ Dp,
    float* __restrict__ yt)
{
    __shared__ float Bsh[64][68];
    const int lane = threadIdx.x & 63;
    const int widx = threadIdx.x >> 6;
    const int b = blockIdx.x >> 9;
    const int d = (blockIdx.x & 511) * 4 + widx;
    const float aL2 = -expf(A_log[(size_t)d * NS + lane]) * 1.44269504f;
    const float Dv = Dp[d];
    const float* dtp = dtt + ((size_t)b * DI + d) * L_DIM;
    const float* xcp = xct + ((size_t)b * DI + d) * L_DIM;
    const float* Bp  = Bss + (size_t)b * L_DIM * NS;
    float* yp = yt + ((size_t)b * DI + d) * L_DIM;
    const int lr = threadIdx.x >> 2;
    const int lc = (threadIdx.x & 3) * 16;
    float h = 0.f;

    for (int t0 = 0; t0 < L_DIM; t0 += 64) {
        const float* bsrc = Bp + (size_t)(t0 + lr) * NS + lc;
        float4 b0 = *(const float4*)(bsrc);
        float4 b1 = *(const float4*)(bsrc + 4);
        float4 b2 = *(const float4*)(bsrc + 8);
        float4 b3 = *(const float4*)(bsrc + 12);
        float dt_v = dtp[t0 + lane];
        float xc_v = xcp[t0 + lane];
        __syncthreads();
        *(float4*)&Bsh[lr][lc]      = b0;
        *(float4*)&Bsh[lr][lc + 4]  = b1;
        *(float4*)&Bsh[lr][lc + 8]  = b2;
        *(float4*)&Bsh[lr][lc + 12] = b3;
        __syncthreads();
        float y_v = 0.f;
        #pragma unroll
        for (int q = 0; q < 64; q += 4) {
            float s0, s1, s2, s3, xs0, xs1, xs2, xs3;
            {   // serial recurrence for 4 steps; exps/loads independent
                float dts, ad;
                dts = rl(dt_v, q+0); xs0 = rl(xc_v, q+0);
                ad = exp2f(aL2 * dts);
                h = fmaf(ad, h, xs0 * Bsh[q+0][lane]); s0 = h;
                dts = rl(dt_v, q+1); xs1 = rl(xc_v, q+1);
                ad = exp2f(aL2 * dts);
                h = fmaf(ad, h, xs1 * Bsh[q+1][lane]); s1 = h;
                dts = rl(dt_v, q+2); xs2 = rl(xc_v, q+2);
                ad = exp2f(aL2 * dts);
                h = fmaf(ad, h, xs2 * Bsh[q+2][lane]); s2 = h;
                dts = rl(dt_v, q+3); xs3 = rl(xc_v, q+3);
                ad = exp2f(aL2 * dts);
                h = fmaf(ad, h, xs3 * Bsh[q+3][lane]); s3 = h;
            }
            // 4 interleaved wave-sum chains (no DPP read-after-write stalls)
            dpp_add4<0x111, 0xf>(s0, s1, s2, s3);   // row_shr:1
            dpp_add4<0x112, 0xf>(s0, s1, s2, s3);   // row_shr:2
            dpp_add4<0x114, 0xf>(s0, s1, s2, s3);   // row_shr:4
            dpp_add4<0x118, 0xf>(s0, s1, s2, s3);   // row_shr:8
            dpp_add4<0x142, 0xa>(s0, s1, s2, s3);   // row_bcast:15
            dpp_add4<0x143, 0xc>(s0, s1, s2, s3);   // row_bcast:31
            float t0v = rl(s0, 63) + Dv * xs0;
            float t1v = rl(s1, 63) + Dv * xs1;
            float t2v = rl(s2, 63) + Dv * xs2;
            float t3v = rl(s3, 63) + Dv * xs3;
            y_v = (lane == q+0) ? t0v : y_v;
            y_v = (lane == q+1) ? t1v : y_v;
            y_v = (lane == q+2) ? t2v : y_v;
            y_v = (lane == q+3) ? t3v : y_v;
        }
        yp[t0 + lane] = y_v;
    }
}

extern "C" void kernel_launch(void* const* d_in, const int* in_sizes, int n_in,
                              void* d_out, int out_size, void* d_ws, size_t ws_size,
                              hipStream_t stream)
{
    const float* x        = (const float*)d_in[0];
    const float* norm_w   = (const float*)d_in[1];
    const float* in_projw = (const float*)d_in[2];
    const float* conv_w   = (const float*)d_in[3];
    const float* conv_b   = (const float*)d_in[4];
    const float* x_projw  = (const float*)d_in[5];
    const float* dt_w     = (const float*)d_in[6];
    const float* dt_b     = (const float*)d_in[7];
    const float* A_log    = (const float*)d_in[8];
    const float* D_param  = (const float*)d_in[9];
    const float* out_projw= (const float*)d_in[10];
    float* out = (float*)d_out;

    float* ws   = (float*)d_ws;
    float* rinv = ws;                               // 4096 (pad)
    float* xr   = rinv + 4096;                      // 8M f32
    float* xc   = xr + (size_t)8*1024*1024;         // 4M f32
    float* dtb  = xc + (size_t)4*1024*1024;         // 4M f32 (yt alias)
    float* Bss  = dtb + (size_t)4*1024*1024;        // 128K f32
    float* dtt  = Bss + 131072;                     // 4M f32
    float* xct  = dtt + (size_t)4*1024*1024;        // 4M f32
    ushort* xn_bf  = (ushort*)(xct + (size_t)4*1024*1024); // 2M u16
    ushort* xc_bf  = xn_bf + (size_t)2*1024*1024;          // 4M u16
    ushort* xpw_bf = xc_bf + (size_t)4*1024*1024;          // 128K u16
    // aliases into dead regions:
    ushort* inpw_bf = (ushort*)dtt;   // dead before dtt written
    ushort* dtw_bf  = (ushort*)xct;   // dead before xct written
    ushort* opw_bf  = xn_bf;          // xn dead after GEMM0
    ushort* y_bf    = (ushort*)xc;    // xc dead after transpose
    float* yt = dtb;

    k_rmsfac<<<2048, 256, 0, stream>>>(x, rinv);
    k_cast_xn<<<1024, 256, 0, stream>>>(x, rinv, norm_w, xn_bf);
    k_cast<<<2048, 256, 0, stream>>>(in_projw, inpw_bf, 524288);
    k_mfma<0><<<dim3(32, 16), 256, 0, stream>>>(xn_bf, inpw_bf, nullptr,
                                                xr, nullptr, nullptr, nullptr, 1024, 4096);
    k_conv<<<4096, 256, 0, stream>>>(xr, conv_w, conv_b, xc, xc_bf);
    k_cast<<<2048, 256, 0, stream>>>(dt_w, dtw_bf, 524288);
    k_cast<<<64, 256, 0, stream>>>(x_projw + (size_t)64*2048, xpw_bf, 16384);
    k_mfma<1><<<dim3(17, 16), 256, 0, stream>>>(xc_bf, dtw_bf, xpw_bf,
                                                dtb, Bss, dt_b, nullptr, 2048, 2048);
    k_tr<<<dim3(32, 16, 2), 256, 0, stream>>>(dtb, dtt, DI, L_DIM,
                                              (size_t)L_DIM*DI, (size_t)DI*L_DIM);
    k_tr<<<dim3(32, 16, 2), 256, 0, stream>>>(xc, xct, DI, L_DIM,
                                              (size_t)L_DIM*DI, (size_t)DI*L_DIM);
    k_scan4<<<1024, 256, 0, stream>>>(dtt, xct, Bss, A_log, D_param, yt);
    k_cast<<<1024, 256, 0, stream>>>(out_projw, opw_bf, 262144);
    k_trg<<<dim3(16, 32, 2), 256, 0, stream>>>(yt, xr, y_bf);
    k_mfma<2><<<dim3(8, 16), 256, 0, stream>>>(y_bf, opw_bf, nullptr,
                                               out, nullptr, nullptr, x, 2048, 1024);
}

// Round 7
// 362.441 us; speedup vs baseline: 4.2496x; 1.1306x over previous
//
#include <hip/hip_runtime.h>
#include <hip/hip_bf16.h>
#include <math.h>

#define L_DIM 1024
#define DM 1024
#define DI 2048
#define NS 64

typedef __attribute__((ext_vector_type(8))) short short8;
typedef __attribute__((ext_vector_type(4))) float f32x4;

// round-to-nearest-even f32 -> bf16 bits
__device__ __forceinline__ ushort bf16u(float f)
{
    unsigned u = __float_as_uint(f);
    unsigned r = (u + 0x7fffu + ((u >> 16) & 1u)) >> 16;
    return (ushort)r;
}

__device__ __forceinline__ void gld16(const ushort* g, const ushort* l)
{
    __builtin_amdgcn_global_load_lds(
        (const __attribute__((address_space(1))) unsigned int*)g,
        (__attribute__((address_space(3))) unsigned int*)l, 16, 0, 0);
}

// ---------------- RMSNorm row factors ----------------------------------------
__global__ __launch_bounds__(256) void k_rmsfac(const float* __restrict__ x,
                                                float* __restrict__ rinv)
{
    int row = blockIdx.x;
    float4 v = ((const float4*)(x + (size_t)row * DM))[threadIdx.x];
    float ss = v.x*v.x + v.y*v.y + v.z*v.z + v.w*v.w;
    #pragma unroll
    for (int m = 32; m; m >>= 1) ss += __shfl_xor(ss, m, 64);
    __shared__ float red[4];
    if ((threadIdx.x & 63) == 0) red[threadIdx.x >> 6] = ss;
    __syncthreads();
    if (threadIdx.x == 0) {
        float tot = red[0] + red[1] + red[2] + red[3];
        rinv[row] = rsqrtf(tot * (1.0f / DM) + 1e-6f);
    }
}

// ---------------- generic f32 -> bf16 cast (8 elems/thread) ------------------
__global__ __launch_bounds__(256) void k_cast(const float* __restrict__ s,
                                              ushort* __restrict__ d, int n8)
{
    int i = blockIdx.x * 256 + threadIdx.x;
    if (i >= n8) return;
    float4 a = ((const float4*)s)[2*i], b = ((const float4*)s)[2*i+1];
    ((ushort4*)d)[2*i]   = make_ushort4(bf16u(a.x), bf16u(a.y), bf16u(a.z), bf16u(a.w));
    ((ushort4*)d)[2*i+1] = make_ushort4(bf16u(b.x), bf16u(b.y), bf16u(b.z), bf16u(b.w));
}

// ---------------- xn = bf16(x * rinv[row] * norm_w[k])  [2048][1024] ---------
__global__ __launch_bounds__(256) void k_cast_xn(const float* __restrict__ x,
    const float* __restrict__ rinv, const float* __restrict__ nw,
    ushort* __restrict__ d)
{
    int i = blockIdx.x * 256 + threadIdx.x;      // 262144 total
    int row = i >> 7, cb = (i & 127) * 8;
    float ri = rinv[row];
    const float* xp = x + (size_t)row * DM + cb;
    float4 a = *(const float4*)xp, b = *(const float4*)(xp + 4);
    float4 wa = *(const float4*)(nw + cb), wb = *(const float4*)(nw + cb + 4);
    ushort* dp = d + (size_t)row * DM + cb;
    *(ushort4*)dp = make_ushort4(bf16u(a.x*ri*wa.x), bf16u(a.y*ri*wa.y),
                                 bf16u(a.z*ri*wa.z), bf16u(a.w*ri*wa.w));
    *(ushort4*)(dp+4) = make_ushort4(bf16u(b.x*ri*wb.x), bf16u(b.y*ri*wb.y),
                                     bf16u(b.z*ri*wb.z), bf16u(b.w*ri*wb.w));
}

// ---------------- MFMA NT GEMM: C[m][n] = sum_k A[m][k]*Bw[n][k] -------------
template<int MODE>
__global__ __launch_bounds__(256) void k_mfma(
    const ushort* __restrict__ Abf, const ushort* __restrict__ Bbf0,
    const ushort* __restrict__ Bbf1, float* __restrict__ C0,
    float* __restrict__ C1, const float* __restrict__ bias,
    const float* __restrict__ skip, int Kdim, int ldc)
{
    __shared__ __align__(16) ushort As[128*32];
    __shared__ __align__(16) ushort Bs[128*32];
    const int t = threadIdx.x, w = t >> 6, lane = t & 63;
    const int nt = blockIdx.x, mt = blockIdx.y;
    const int mBase = mt * 128, nBase = nt * 128;
    const bool isXP = (MODE == 1) && (nt == 16);
    const ushort* __restrict__ Bbf = isXP ? Bbf1 : Bbf0;
    const int wr = (w >> 1) * 64, wc = (w & 1) * 64;
    const int sR = lane >> 2, sK = (lane & 3) * 8;

    f32x4 acc[4][4];
    #pragma unroll
    for (int i = 0; i < 4; ++i)
        #pragma unroll
        for (int j = 0; j < 4; ++j)
            acc[i][j] = (f32x4){0.f, 0.f, 0.f, 0.f};

    for (int kt = 0; kt < Kdim; kt += 32) {
        #pragma unroll
        for (int s = 0; s < 2; ++s) {
            int tr = w*32 + s*16 + sR;
            gld16(Abf + (size_t)(mBase + tr) * Kdim + kt + sK,
                  As + (w*32 + s*16) * 32);
            int gr = isXP ? (tr < 63 ? tr : 63) : (nBase + tr);
            gld16(Bbf + (size_t)gr * Kdim + kt + sK,
                  Bs + (w*32 + s*16) * 32);
        }
        __syncthreads();
        short8 af[4], bfr[4];
        #pragma unroll
        for (int f = 0; f < 4; ++f) {
            af[f]  = *(const short8*)(As + (wr + f*16 + (lane & 15))*32 + (lane >> 4)*8);
            bfr[f] = *(const short8*)(Bs + (wc + f*16 + (lane & 15))*32 + (lane >> 4)*8);
        }
        #pragma unroll
        for (int mi = 0; mi < 4; ++mi)
            #pragma unroll
            for (int ni = 0; ni < 4; ++ni)
                acc[mi][ni] = __builtin_amdgcn_mfma_f32_16x16x32_bf16(
                    af[mi], bfr[ni], acc[mi][ni], 0, 0, 0);
        __syncthreads();
    }

    const int rb = (lane >> 4) * 4, cbl = lane & 15;
    #pragma unroll
    for (int mi = 0; mi < 4; ++mi) {
        #pragma unroll
        for (int ni = 0; ni < 4; ++ni) {
            int ltcol = wc + ni*16 + cbl;
            int col = nBase + ltcol;
            #pragma unroll
            for (int j = 0; j < 4; ++j) {
                int row = mBase + wr + mi*16 + rb + j;
                float v = acc[mi][ni][j];
                if constexpr (MODE == 0) {
                    C0[(size_t)row * ldc + col] = v;
                } else if constexpr (MODE == 1) {
                    if (isXP) {
                        if (ltcol < NS) C1[(size_t)row * NS + ltcol] = v;
                    } else {
                        float z = v + bias[col];
                        C0[(size_t)row * ldc + col] =
                            (z > 20.f) ? z : logf(1.f + expf(z));
                    }
                } else {
                    C0[(size_t)row * ldc + col] = v + skip[(size_t)row * ldc + col];
                }
            }
        }
    }
}

// ---------------- causal depthwise conv1d (K=4) + SiLU, f32 + bf16 out -------
__global__ __launch_bounds__(256) void k_conv(const float* __restrict__ xr,
    const float* __restrict__ cw, const float* __restrict__ cb,
    float* __restrict__ xc, ushort* __restrict__ xcb)
{
    int gid = blockIdx.x * 256 + threadIdx.x;      // [0, 2*1024*512)
    int d = (gid & 511) * 4;
    int tt = (gid >> 9) & 1023;
    int b = gid >> 19;
    float4 w[4];
    #pragma unroll
    for (int c = 0; c < 4; ++c) w[c] = *(const float4*)(cw + (size_t)(d + c) * 4);
    float4 acc = *(const float4*)(cb + d);
    const float* base = xr + (size_t)b * L_DIM * (2*DI) + d;
    #pragma unroll
    for (int j = 0; j < 4; ++j) {
        int ti = tt - 3 + j;
        if (ti < 0) continue;
        float4 xv = *(const float4*)(base + (size_t)ti * (2*DI));
        const float* w0 = (const float*)&w[0];
        const float* w1 = (const float*)&w[1];
        const float* w2 = (const float*)&w[2];
        const float* w3 = (const float*)&w[3];
        acc.x = fmaf(w0[j], xv.x, acc.x);
        acc.y = fmaf(w1[j], xv.y, acc.y);
        acc.z = fmaf(w2[j], xv.z, acc.z);
        acc.w = fmaf(w3[j], xv.w, acc.w);
    }
    acc.x = acc.x / (1.f + expf(-acc.x));
    acc.y = acc.y / (1.f + expf(-acc.y));
    acc.z = acc.z / (1.f + expf(-acc.z));
    acc.w = acc.w / (1.f + expf(-acc.w));
    size_t o = (size_t)(b * L_DIM + tt) * DI + d;
    *(float4*)(xc + o) = acc;
    *(ushort4*)(xcb + o) = make_ushort4(bf16u(acc.x), bf16u(acc.y),
                                        bf16u(acc.z), bf16u(acc.w));
}

// ---------------- tiled transpose: dst[c][r] = src[r][c], batched ------------
__global__ __launch_bounds__(256) void k_tr(const float* __restrict__ src,
    float* __restrict__ dst, int srs, int drs, size_t sB, size_t dB)
{
    __shared__ float tile[64][65];
    const int r0 = blockIdx.y * 64, c0 = blockIdx.x * 64;
    const float* s = src + blockIdx.z * sB;
    float* d = dst + blockIdx.z * dB;
    const int tx = threadIdx.x & 15, ty = threadIdx.x >> 4;
    #pragma unroll
    for (int p = 0; p < 4; ++p) {
        float4 v = *(const float4*)(s + (size_t)(r0 + ty + p*16) * srs + c0 + tx*4);
        tile[ty + p*16][tx*4+0] = v.x; tile[ty + p*16][tx*4+1] = v.y;
        tile[ty + p*16][tx*4+2] = v.z; tile[ty + p*16][tx*4+3] = v.w;
    }
    __syncthreads();
    #pragma unroll
    for (int p = 0; p < 4; ++p) {
        int oc = ty + p*16;
        float4 v = make_float4(tile[tx*4+0][oc], tile[tx*4+1][oc],
                               tile[tx*4+2][oc], tile[tx*4+3][oc]);
        *(float4*)(d + (size_t)(c0 + oc) * drs + r0 + tx*4) = v;
    }
}

// ------ back-transpose yt[b][d][t] -> y_bf[b*t][d], fused silu(res) gate -----
__global__ __launch_bounds__(256) void k_trg(const float* __restrict__ yt,
    const float* __restrict__ xr, ushort* __restrict__ ybf)
{
    __shared__ float tile[64][65];
    const int r0 = blockIdx.y * 64, c0 = blockIdx.x * 64;   // r=d, c=t
    const int z = blockIdx.z;
    const float* s = yt + (size_t)z * DI * L_DIM;
    const int tx = threadIdx.x & 15, ty = threadIdx.x >> 4;
    #pragma unroll
    for (int p = 0; p < 4; ++p) {
        float4 v = *(const float4*)(s + (size_t)(r0 + ty + p*16) * L_DIM + c0 + tx*4);
        tile[ty + p*16][tx*4+0] = v.x; tile[ty + p*16][tx*4+1] = v.y;
        tile[ty + p*16][tx*4+2] = v.z; tile[ty + p*16][tx*4+3] = v.w;
    }
    __syncthreads();
    #pragma unroll
    for (int p = 0; p < 4; ++p) {
        int oc = ty + p*16;                       // local t index
        int row = z * L_DIM + c0 + oc;            // global (b*t) row
        float4 v = make_float4(tile[tx*4+0][oc], tile[tx*4+1][oc],
                               tile[tx*4+2][oc], tile[tx*4+3][oc]);
        float4 g = *(const float4*)(xr + (size_t)row * (2*DI) + DI + r0 + tx*4);
        v.x *= g.x / (1.f + expf(-g.x));
        v.y *= g.y / (1.f + expf(-g.y));
        v.z *= g.z / (1.f + expf(-g.z));
        v.w *= g.w / (1.f + expf(-g.w));
        *(ushort4*)(ybf + (size_t)row * DI + r0 + tx*4) =
            make_ushort4(bf16u(v.x), bf16u(v.y), bf16u(v.z), bf16u(v.w));
    }
}

__device__ __forceinline__ float rl(float v, int lane)
{
    return __int_as_float(__builtin_amdgcn_readlane(__float_as_int(v), lane));
}

// ---------------- selective scan v5: fused v_add_f32_dpp reduce --------------
// Per 4-step group: recurrence in HIP, then ONE asm block with 4 interleaved
// 6-stage fused-DPP sum chains (+ 4 readlanes). Same-register def-use gap = 3
// everywhere (>= 2 required DPP wait states). Totals are wave-uniform ->
// written into lane q+i of y_v via v_writelane_b32 (asm; no builtin exists).
__global__ __launch_bounds__(256) void k_scan5(const float* __restrict__ dtt,
    const float* __restrict__ xct, const float* __restrict__ Bss,
    const float* __restrict__ A_log, const float* __restrict__ Dp,
    float* __restrict__ yt)
{
    __shared__ float Bsh[64][68];
    const int lane = threadIdx.x & 63;
    const int widx = threadIdx.x >> 6;
    const int b = blockIdx.x >> 9;
    const int d = (blockIdx.x & 511) * 4 + widx;
    const float aL2 = -expf(A_log[(size_t)d * NS + lane]) * 1.44269504f;
    const float Dv = Dp[d];
    const float* dtp = dtt + ((size_t)b * DI + d) * L_DIM;
    const float* xcp = xct + ((size_t)b * DI + d) * L_DIM;
    const float* Bp  = Bss + (size_t)b * L_DIM * NS;
    float* yp = yt + ((size_t)b * DI + d) * L_DIM;
    const int lr = threadIdx.x >> 2;
    const int lc = (threadIdx.x & 3) * 16;
    float h = 0.f;

    for (int t0 = 0; t0 < L_DIM; t0 += 64) {
        const float* bsrc = Bp + (size_t)(t0 + lr) * NS + lc;
        float4 b0 = *(const float4*)(bsrc);
        float4 b1 = *(const float4*)(bsrc + 4);
        float4 b2 = *(const float4*)(bsrc + 8);
        float4 b3 = *(const float4*)(bsrc + 12);
        float dt_v = dtp[t0 + lane];
        float xc_v = xcp[t0 + lane];
        __syncthreads();
        *(float4*)&Bsh[lr][lc]      = b0;
        *(float4*)&Bsh[lr][lc + 4]  = b1;
        *(float4*)&Bsh[lr][lc + 8]  = b2;
        *(float4*)&Bsh[lr][lc + 12] = b3;
        __syncthreads();
        float y_v = 0.f;
        #pragma unroll
        for (int q = 0; q < 64; q += 4) {
            float s0, s1, s2, s3;
            float dts, ad;
            dts = rl(dt_v, q+0);
            ad = exp2f(aL2 * dts);
            h = fmaf(ad, h, rl(xc_v, q+0) * Bsh[q+0][lane]); s0 = h;
            dts = rl(dt_v, q+1);
            ad = exp2f(aL2 * dts);
            h = fmaf(ad, h, rl(xc_v, q+1) * Bsh[q+1][lane]); s1 = h;
            dts = rl(dt_v, q+2);
            ad = exp2f(aL2 * dts);
            h = fmaf(ad, h, rl(xc_v, q+2) * Bsh[q+2][lane]); s2 = h;
            dts = rl(dt_v, q+3);
            ad = exp2f(aL2 * dts);
            h = fmaf(ad, h, rl(xc_v, q+3) * Bsh[q+3][lane]); s3 = h;
            int tot0, tot1, tot2, tot3;
            asm("v_add_f32_dpp %0, %0, %0 row_shr:1 row_mask:0xf bank_mask:0xf\n\t"
                "v_add_f32_dpp %1, %1, %1 row_shr:1 row_mask:0xf bank_mask:0xf\n\t"
                "v_add_f32_dpp %2, %2, %2 row_shr:1 row_mask:0xf bank_mask:0xf\n\t"
                "v_add_f32_dpp %3, %3, %3 row_shr:1 row_mask:0xf bank_mask:0xf\n\t"
                "v_add_f32_dpp %0, %0, %0 row_shr:2 row_mask:0xf bank_mask:0xf\n\t"
                "v_add_f32_dpp %1, %1, %1 row_shr:2 row_mask:0xf bank_mask:0xf\n\t"
                "v_add_f32_dpp %2, %2, %2 row_shr:2 row_mask:0xf bank_mask:0xf\n\t"
                "v_add_f32_dpp %3, %3, %3 row_shr:2 row_mask:0xf bank_mask:0xf\n\t"
                "v_add_f32_dpp %0, %0, %0 row_shr:4 row_mask:0xf bank_mask:0xf\n\t"
                "v_add_f32_dpp %1, %1, %1 row_shr:4 row_mask:0xf bank_mask:0xf\n\t"
                "v_add_f32_dpp %2, %2, %2 row_shr:4 row_mask:0xf bank_mask:0xf\n\t"
                "v_add_f32_dpp %3, %3, %3 row_shr:4 row_mask:0xf bank_mask:0xf\n\t"
                "v_add_f32_dpp %0, %0, %0 row_shr:8 row_mask:0xf bank_mask:0xf\n\t"
                "v_add_f32_dpp %1, %1, %1 row_shr:8 row_mask:0xf bank_mask:0xf\n\t"
                "v_add_f32_dpp %2, %2, %2 row_shr:8 row_mask:0xf bank_mask:0xf\n\t"
                "v_add_f32_dpp %3, %3, %3 row_shr:8 row_mask:0xf bank_mask:0xf\n\t"
                "v_add_f32_dpp %0, %0, %0 row_bcast:15 row_mask:0xa bank_mask:0xf\n\t"
                "v_add_f32_dpp %1, %1, %1 row_bcast:15 row_mask:0xa bank_mask:0xf\n\t"
                "v_add_f32_dpp %2, %2, %2 row_bcast:15 row_mask:0xa bank_mask:0xf\n\t"
                "v_add_f32_dpp %3, %3, %3 row_bcast:15 row_mask:0xa bank_mask:0xf\n\t"
                "v_add_f32_dpp %0, %0, %0 row_bcast:31 row_mask:0xc bank_mask:0xf\n\t"
                "v_add_f32_dpp %1, %1, %1 row_bcast:31 row_mask:0xc bank_mask:0xf\n\t"
                "v_add_f32_dpp %2, %2, %2 row_bcast:31 row_mask:0xc bank_mask:0xf\n\t"
                "v_add_f32_dpp %3, %3, %3 row_bcast:31 row_mask:0xc bank_mask:0xf\n\t"
                "v_readlane_b32 %4, %0, 63\n\t"
                "v_readlane_b32 %5, %1, 63\n\t"
                "v_readlane_b32 %6, %2, 63\n\t"
                "v_readlane_b32 %7, %3, 63"
                : "+v"(s0), "+v"(s1), "+v"(s2), "+v"(s3),
                  "=s"(tot0), "=s"(tot1), "=s"(tot2), "=s"(tot3));
            asm("v_writelane_b32 %0, %1, %2"
                : "+v"(y_v) : "s"(tot0), "i"(q+0));
            asm("v_writelane_b32 %0, %1, %2"
                : "+v"(y_v) : "s"(tot1), "i"(q+1));
            asm("v_writelane_b32 %0, %1, %2"
                : "+v"(y_v) : "s"(tot2), "i"(q+2));
            asm("v_writelane_b32 %0, %1, %2"
                : "+v"(y_v) : "s"(tot3), "i"(q+3));
        }
        yp[t0 + lane] = fmaf(Dv, xc_v, y_v);
    }
}

extern "C" void kernel_launch(void* const* d_in, const int* in_sizes, int n_in,
                              void* d_out, int out_size, void* d_ws, size_t ws_size,
                              hipStream_t stream)
{
    const float* x        = (const float*)d_in[0];
    const float* norm_w   = (const float*)d_in[1];
    const float* in_projw = (const float*)d_in[2];
    const float* conv_w   = (const float*)d_in[3];
    const float* conv_b   = (const float*)d_in[4];
    const float* x_projw  = (const float*)d_in[5];
    const float* dt_w     = (const float*)d_in[6];
    const float* dt_b     = (const float*)d_in[7];
    const float* A_log    = (const float*)d_in[8];
    const float* D_param  = (const float*)d_in[9];
    const float* out_projw= (const float*)d_in[10];
    float* out = (float*)d_out;

    float* ws   = (float*)d_ws;
    float* rinv = ws;                               // 4096 (pad)
    float* xr   = rinv + 4096;                      // 8M f32
    float* xc   = xr + (size_t)8*1024*1024;         // 4M f32
    float* dtb  = xc + (size_t)4*1024*1024;         // 4M f32 (yt alias)
    float* Bss  = dtb + (size_t)4*1024*1024;        // 128K f32
    float* dtt  = Bss + 131072;                     // 4M f32
    float* xct  = dtt + (size_t)4*1024*1024;        // 4M f32
    ushort* xn_bf  = (ushort*)(xct + (size_t)4*1024*1024); // 2M u16
    ushort* xc_bf  = xn_bf + (size_t)2*1024*1024;          // 4M u16
    ushort* xpw_bf = xc_bf + (size_t)4*1024*1024;          // 128K u16
    // aliases into dead regions:
    ushort* inpw_bf = (ushort*)dtt;   // dead before dtt written
    ushort* dtw_bf  = (ushort*)xct;   // dead before xct written
    ushort* opw_bf  = xn_bf;          // xn dead after GEMM0
    ushort* y_bf    = (ushort*)xc;    // xc dead after transpose
    float* yt = dtb;

    k_rmsfac<<<2048, 256, 0, stream>>>(x, rinv);
    k_cast_xn<<<1024, 256, 0, stream>>>(x, rinv, norm_w, xn_bf);
    k_cast<<<2048, 256, 0, stream>>>(in_projw, inpw_bf, 524288);
    k_mfma<0><<<dim3(32, 16), 256, 0, stream>>>(xn_bf, inpw_bf, nullptr,
                                                xr, nullptr, nullptr, nullptr, 1024, 4096);
    k_conv<<<4096, 256, 0, stream>>>(xr, conv_w, conv_b, xc, xc_bf);
    k_cast<<<2048, 256, 0, stream>>>(dt_w, dtw_bf, 524288);
    k_cast<<<64, 256, 0, stream>>>(x_projw + (size_t)64*2048, xpw_bf, 16384);
    k_mfma<1><<<dim3(17, 16), 256, 0, stream>>>(xc_bf, dtw_bf, xpw_bf,
                                                dtb, Bss, dt_b, nullptr, 2048, 2048);
    k_tr<<<dim3(32, 16, 2), 256, 0, stream>>>(dtb, dtt, DI, L_DIM,
                                              (size_t)L_DIM*DI, (size_t)DI*L_DIM);
    k_tr<<<dim3(32, 16, 2), 256, 0, stream>>>(xc, xct, DI, L_DIM,
                                              (size_t)L_DIM*DI, (size_t)DI*L_DIM);
    k_scan5<<<1024, 256, 0, stream>>>(dtt, xct, Bss, A_log, D_param, yt);
    k_cast<<<1024, 256, 0, stream>>>(out_projw, opw_bf, 262144);
    k_trg<<<dim3(16, 32, 2), 256, 0, stream>>>(yt, xr, y_bf);
    k_mfma<2><<<dim3(8, 16), 256, 0, stream>>>(y_bf, opw_bf, nullptr,
                                               out, nullptr, nullptr, x, 2048, 1024);
}

// Round 8
// 332.528 us; speedup vs baseline: 4.6319x; 1.0900x over previous
//
#include <hip/hip_runtime.h>
#include <hip/hip_bf16.h>
#include <math.h>

#define L_DIM 1024
#define DM 1024
#define DI 2048
#define NS 64

typedef __attribute__((ext_vector_type(8))) short short8;
typedef __attribute__((ext_vector_type(4))) float f32x4;

// round-to-nearest-even f32 -> bf16 bits
__device__ __forceinline__ ushort bf16u(float f)
{
    unsigned u = __float_as_uint(f);
    unsigned r = (u + 0x7fffu + ((u >> 16) & 1u)) >> 16;
    return (ushort)r;
}

__device__ __forceinline__ void gld16(const ushort* g, const ushort* l)
{
    __builtin_amdgcn_global_load_lds(
        (const __attribute__((address_space(1))) unsigned int*)g,
        (__attribute__((address_space(3))) unsigned int*)l, 16, 0, 0);
}

// ---------------- RMSNorm row factors ----------------------------------------
__global__ __launch_bounds__(256) void k_rmsfac(const float* __restrict__ x,
                                                float* __restrict__ rinv)
{
    int row = blockIdx.x;
    float4 v = ((const float4*)(x + (size_t)row * DM))[threadIdx.x];
    float ss = v.x*v.x + v.y*v.y + v.z*v.z + v.w*v.w;
    #pragma unroll
    for (int m = 32; m; m >>= 1) ss += __shfl_xor(ss, m, 64);
    __shared__ float red[4];
    if ((threadIdx.x & 63) == 0) red[threadIdx.x >> 6] = ss;
    __syncthreads();
    if (threadIdx.x == 0) {
        float tot = red[0] + red[1] + red[2] + red[3];
        rinv[row] = rsqrtf(tot * (1.0f / DM) + 1e-6f);
    }
}

// ---------------- generic f32 -> bf16 cast (8 elems/thread) ------------------
__global__ __launch_bounds__(256) void k_cast(const float* __restrict__ s,
                                              ushort* __restrict__ d, int n8)
{
    int i = blockIdx.x * 256 + threadIdx.x;
    if (i >= n8) return;
    float4 a = ((const float4*)s)[2*i], b = ((const float4*)s)[2*i+1];
    ((ushort4*)d)[2*i]   = make_ushort4(bf16u(a.x), bf16u(a.y), bf16u(a.z), bf16u(a.w));
    ((ushort4*)d)[2*i+1] = make_ushort4(bf16u(b.x), bf16u(b.y), bf16u(b.z), bf16u(b.w));
}

// ---------------- xn = bf16(x * rinv[row] * norm_w[k])  [2048][1024] ---------
__global__ __launch_bounds__(256) void k_cast_xn(const float* __restrict__ x,
    const float* __restrict__ rinv, const float* __restrict__ nw,
    ushort* __restrict__ d)
{
    int i = blockIdx.x * 256 + threadIdx.x;      // 262144 total
    int row = i >> 7, cb = (i & 127) * 8;
    float ri = rinv[row];
    const float* xp = x + (size_t)row * DM + cb;
    float4 a = *(const float4*)xp, b = *(const float4*)(xp + 4);
    float4 wa = *(const float4*)(nw + cb), wb = *(const float4*)(nw + cb + 4);
    ushort* dp = d + (size_t)row * DM + cb;
    *(ushort4*)dp = make_ushort4(bf16u(a.x*ri*wa.x), bf16u(a.y*ri*wa.y),
                                 bf16u(a.z*ri*wa.z), bf16u(a.w*ri*wa.w));
    *(ushort4*)(dp+4) = make_ushort4(bf16u(b.x*ri*wb.x), bf16u(b.y*ri*wb.y),
                                     bf16u(b.z*ri*wb.z), bf16u(b.w*ri*wb.w));
}

// ---------------- MFMA NT GEMM: C[m][n] = sum_k A[m][k]*Bw[n][k] -------------
template<int MODE>
__global__ __launch_bounds__(256) void k_mfma(
    const ushort* __restrict__ Abf, const ushort* __restrict__ Bbf0,
    const ushort* __restrict__ Bbf1, float* __restrict__ C0,
    float* __restrict__ C1, const float* __restrict__ bias,
    const float* __restrict__ skip, int Kdim, int ldc)
{
    __shared__ __align__(16) ushort As[128*32];
    __shared__ __align__(16) ushort Bs[128*32];
    const int t = threadIdx.x, w = t >> 6, lane = t & 63;
    const int nt = blockIdx.x, mt = blockIdx.y;
    const int mBase = mt * 128, nBase = nt * 128;
    const bool isXP = (MODE == 1) && (nt == 16);
    const ushort* __restrict__ Bbf = isXP ? Bbf1 : Bbf0;
    const int wr = (w >> 1) * 64, wc = (w & 1) * 64;
    const int sR = lane >> 2, sK = (lane & 3) * 8;

    f32x4 acc[4][4];
    #pragma unroll
    for (int i = 0; i < 4; ++i)
        #pragma unroll
        for (int j = 0; j < 4; ++j)
            acc[i][j] = (f32x4){0.f, 0.f, 0.f, 0.f};

    for (int kt = 0; kt < Kdim; kt += 32) {
        #pragma unroll
        for (int s = 0; s < 2; ++s) {
            int tr = w*32 + s*16 + sR;
            gld16(Abf + (size_t)(mBase + tr) * Kdim + kt + sK,
                  As + (w*32 + s*16) * 32);
            int gr = isXP ? (tr < 63 ? tr : 63) : (nBase + tr);
            gld16(Bbf + (size_t)gr * Kdim + kt + sK,
                  Bs + (w*32 + s*16) * 32);
        }
        __syncthreads();
        short8 af[4], bfr[4];
        #pragma unroll
        for (int f = 0; f < 4; ++f) {
            af[f]  = *(const short8*)(As + (wr + f*16 + (lane & 15))*32 + (lane >> 4)*8);
            bfr[f] = *(const short8*)(Bs + (wc + f*16 + (lane & 15))*32 + (lane >> 4)*8);
        }
        #pragma unroll
        for (int mi = 0; mi < 4; ++mi)
            #pragma unroll
            for (int ni = 0; ni < 4; ++ni)
                acc[mi][ni] = __builtin_amdgcn_mfma_f32_16x16x32_bf16(
                    af[mi], bfr[ni], acc[mi][ni], 0, 0, 0);
        __syncthreads();
    }

    const int rb = (lane >> 4) * 4, cbl = lane & 15;
    #pragma unroll
    for (int mi = 0; mi < 4; ++mi) {
        #pragma unroll
        for (int ni = 0; ni < 4; ++ni) {
            int ltcol = wc + ni*16 + cbl;
            int col = nBase + ltcol;
            #pragma unroll
            for (int j = 0; j < 4; ++j) {
                int row = mBase + wr + mi*16 + rb + j;
                float v = acc[mi][ni][j];
                if constexpr (MODE == 0) {
                    C0[(size_t)row * ldc + col] = v;
                } else if constexpr (MODE == 1) {
                    if (isXP) {
                        if (ltcol < NS) C1[(size_t)row * NS + ltcol] = v;
                    } else {
                        float z = v + bias[col];
                        C0[(size_t)row * ldc + col] =
                            (z > 20.f) ? z : logf(1.f + expf(z));
                    }
                } else {
                    C0[(size_t)row * ldc + col] = v + skip[(size_t)row * ldc + col];
                }
            }
        }
    }
}

// ---------------- causal depthwise conv1d (K=4) + SiLU, f32 + bf16 out -------
__global__ __launch_bounds__(256) void k_conv(const float* __restrict__ xr,
    const float* __restrict__ cw, const float* __restrict__ cb,
    float* __restrict__ xc, ushort* __restrict__ xcb)
{
    int gid = blockIdx.x * 256 + threadIdx.x;      // [0, 2*1024*512)
    int d = (gid & 511) * 4;
    int tt = (gid >> 9) & 1023;
    int b = gid >> 19;
    float4 w[4];
    #pragma unroll
    for (int c = 0; c < 4; ++c) w[c] = *(const float4*)(cw + (size_t)(d + c) * 4);
    float4 acc = *(const float4*)(cb + d);
    const float* base = xr + (size_t)b * L_DIM * (2*DI) + d;
    #pragma unroll
    for (int j = 0; j < 4; ++j) {
        int ti = tt - 3 + j;
        if (ti < 0) continue;
        float4 xv = *(const float4*)(base + (size_t)ti * (2*DI));
        const float* w0 = (const float*)&w[0];
        const float* w1 = (const float*)&w[1];
        const float* w2 = (const float*)&w[2];
        const float* w3 = (const float*)&w[3];
        acc.x = fmaf(w0[j], xv.x, acc.x);
        acc.y = fmaf(w1[j], xv.y, acc.y);
        acc.z = fmaf(w2[j], xv.z, acc.z);
        acc.w = fmaf(w3[j], xv.w, acc.w);
    }
    acc.x = acc.x / (1.f + expf(-acc.x));
    acc.y = acc.y / (1.f + expf(-acc.y));
    acc.z = acc.z / (1.f + expf(-acc.z));
    acc.w = acc.w / (1.f + expf(-acc.w));
    size_t o = (size_t)(b * L_DIM + tt) * DI + d;
    *(float4*)(xc + o) = acc;
    *(ushort4*)(xcb + o) = make_ushort4(bf16u(acc.x), bf16u(acc.y),
                                        bf16u(acc.z), bf16u(acc.w));
}

// ---------------- tiled transpose: dst[c][r] = src[r][c], batched ------------
__global__ __launch_bounds__(256) void k_tr(const float* __restrict__ src,
    float* __restrict__ dst, int srs, int drs, size_t sB, size_t dB)
{
    __shared__ float tile[64][65];
    const int r0 = blockIdx.y * 64, c0 = blockIdx.x * 64;
    const float* s = src + blockIdx.z * sB;
    float* d = dst + blockIdx.z * dB;
    const int tx = threadIdx.x & 15, ty = threadIdx.x >> 4;
    #pragma unroll
    for (int p = 0; p < 4; ++p) {
        float4 v = *(const float4*)(s + (size_t)(r0 + ty + p*16) * srs + c0 + tx*4);
        tile[ty + p*16][tx*4+0] = v.x; tile[ty + p*16][tx*4+1] = v.y;
        tile[ty + p*16][tx*4+2] = v.z; tile[ty + p*16][tx*4+3] = v.w;
    }
    __syncthreads();
    #pragma unroll
    for (int p = 0; p < 4; ++p) {
        int oc = ty + p*16;
        float4 v = make_float4(tile[tx*4+0][oc], tile[tx*4+1][oc],
                               tile[tx*4+2][oc], tile[tx*4+3][oc]);
        *(float4*)(d + (size_t)(c0 + oc) * drs + r0 + tx*4) = v;
    }
}

// ------ back-transpose yt[b][d][t] -> y_bf[b*t][d], fused silu(res) gate -----
__global__ __launch_bounds__(256) void k_trg(const float* __restrict__ yt,
    const float* __restrict__ xr, ushort* __restrict__ ybf)
{
    __shared__ float tile[64][65];
    const int r0 = blockIdx.y * 64, c0 = blockIdx.x * 64;   // r=d, c=t
    const int z = blockIdx.z;
    const float* s = yt + (size_t)z * DI * L_DIM;
    const int tx = threadIdx.x & 15, ty = threadIdx.x >> 4;
    #pragma unroll
    for (int p = 0; p < 4; ++p) {
        float4 v = *(const float4*)(s + (size_t)(r0 + ty + p*16) * L_DIM + c0 + tx*4);
        tile[ty + p*16][tx*4+0] = v.x; tile[ty + p*16][tx*4+1] = v.y;
        tile[ty + p*16][tx*4+2] = v.z; tile[ty + p*16][tx*4+3] = v.w;
    }
    __syncthreads();
    #pragma unroll
    for (int p = 0; p < 4; ++p) {
        int oc = ty + p*16;                       // local t index
        int row = z * L_DIM + c0 + oc;            // global (b*t) row
        float4 v = make_float4(tile[tx*4+0][oc], tile[tx*4+1][oc],
                               tile[tx*4+2][oc], tile[tx*4+3][oc]);
        float4 g = *(const float4*)(xr + (size_t)row * (2*DI) + DI + r0 + tx*4);
        v.x *= g.x / (1.f + expf(-g.x));
        v.y *= g.y / (1.f + expf(-g.y));
        v.z *= g.z / (1.f + expf(-g.z));
        v.w *= g.w / (1.f + expf(-g.w));
        *(ushort4*)(ybf + (size_t)row * DI + r0 + tx*4) =
            make_ushort4(bf16u(v.x), bf16u(v.y), bf16u(v.z), bf16u(v.w));
    }
}

__device__ __forceinline__ float rl(float v, int lane)
{
    return __int_as_float(__builtin_amdgcn_readlane(__float_as_int(v), lane));
}
// native 2^x — single v_exp_f32 (library exp2f is a multi-instruction call)
__device__ __forceinline__ float exp2_fast(float x)
{
    float r;
    asm("v_exp_f32 %0, %1" : "=v"(r) : "v"(x));
    return r;
}

// ---------------- selective scan v6: native v_exp + fused DPP reduce ---------
__global__ __launch_bounds__(256) void k_scan6(const float* __restrict__ dtt,
    const float* __restrict__ xct, const float* __restrict__ Bss,
    const float* __restrict__ A_log, const float* __restrict__ Dp,
    float* __restrict__ yt)
{
    __shared__ float Bsh[64][68];
    const int lane = threadIdx.x & 63;
    const int widx = threadIdx.x >> 6;
    const int b = blockIdx.x >> 9;
    const int d = (blockIdx.x & 511) * 4 + widx;
    const float aL2 = -expf(A_log[(size_t)d * NS + lane]) * 1.44269504f;
    const float Dv = Dp[d];
    const float* dtp = dtt + ((size_t)b * DI + d) * L_DIM;
    const float* xcp = xct + ((size_t)b * DI + d) * L_DIM;
    const float* Bp  = Bss + (size_t)b * L_DIM * NS;
    float* yp = yt + ((size_t)b * DI + d) * L_DIM;
    const int lr = threadIdx.x >> 2;
    const int lc = (threadIdx.x & 3) * 16;
    float h = 0.f;

    for (int t0 = 0; t0 < L_DIM; t0 += 64) {
        const float* bsrc = Bp + (size_t)(t0 + lr) * NS + lc;
        float4 b0 = *(const float4*)(bsrc);
        float4 b1 = *(const float4*)(bsrc + 4);
        float4 b2 = *(const float4*)(bsrc + 8);
        float4 b3 = *(const float4*)(bsrc + 12);
        float dt_v = dtp[t0 + lane];
        float xc_v = xcp[t0 + lane];
        __syncthreads();
        *(float4*)&Bsh[lr][lc]      = b0;
        *(float4*)&Bsh[lr][lc + 4]  = b1;
        *(float4*)&Bsh[lr][lc + 8]  = b2;
        *(float4*)&Bsh[lr][lc + 12] = b3;
        __syncthreads();
        float y_v = 0.f;
        #pragma unroll
        for (int q = 0; q < 64; q += 4) {
            float s0, s1, s2, s3;
            {
                float p, ad;
                p  = rl(xc_v, q+0) * Bsh[q+0][lane];
                ad = exp2_fast(aL2 * rl(dt_v, q+0));
                h = fmaf(ad, h, p); s0 = h;
                p  = rl(xc_v, q+1) * Bsh[q+1][lane];
                ad = exp2_fast(aL2 * rl(dt_v, q+1));
                h = fmaf(ad, h, p); s1 = h;
                p  = rl(xc_v, q+2) * Bsh[q+2][lane];
                ad = exp2_fast(aL2 * rl(dt_v, q+2));
                h = fmaf(ad, h, p); s2 = h;
                p  = rl(xc_v, q+3) * Bsh[q+3][lane];
                ad = exp2_fast(aL2 * rl(dt_v, q+3));
                h = fmaf(ad, h, p); s3 = h;
            }
            int tot0, tot1, tot2, tot3;
            asm("v_add_f32_dpp %0, %0, %0 row_shr:1 row_mask:0xf bank_mask:0xf\n\t"
                "v_add_f32_dpp %1, %1, %1 row_shr:1 row_mask:0xf bank_mask:0xf\n\t"
                "v_add_f32_dpp %2, %2, %2 row_shr:1 row_mask:0xf bank_mask:0xf\n\t"
                "v_add_f32_dpp %3, %3, %3 row_shr:1 row_mask:0xf bank_mask:0xf\n\t"
                "v_add_f32_dpp %0, %0, %0 row_shr:2 row_mask:0xf bank_mask:0xf\n\t"
                "v_add_f32_dpp %1, %1, %1 row_shr:2 row_mask:0xf bank_mask:0xf\n\t"
                "v_add_f32_dpp %2, %2, %2 row_shr:2 row_mask:0xf bank_mask:0xf\n\t"
                "v_add_f32_dpp %3, %3, %3 row_shr:2 row_mask:0xf bank_mask:0xf\n\t"
                "v_add_f32_dpp %0, %0, %0 row_shr:4 row_mask:0xf bank_mask:0xf\n\t"
                "v_add_f32_dpp %1, %1, %1 row_shr:4 row_mask:0xf bank_mask:0xf\n\t"
                "v_add_f32_dpp %2, %2, %2 row_shr:4 row_mask:0xf bank_mask:0xf\n\t"
                "v_add_f32_dpp %3, %3, %3 row_shr:4 row_mask:0xf bank_mask:0xf\n\t"
                "v_add_f32_dpp %0, %0, %0 row_shr:8 row_mask:0xf bank_mask:0xf\n\t"
                "v_add_f32_dpp %1, %1, %1 row_shr:8 row_mask:0xf bank_mask:0xf\n\t"
                "v_add_f32_dpp %2, %2, %2 row_shr:8 row_mask:0xf bank_mask:0xf\n\t"
                "v_add_f32_dpp %3, %3, %3 row_shr:8 row_mask:0xf bank_mask:0xf\n\t"
                "v_add_f32_dpp %0, %0, %0 row_bcast:15 row_mask:0xa bank_mask:0xf\n\t"
                "v_add_f32_dpp %1, %1, %1 row_bcast:15 row_mask:0xa bank_mask:0xf\n\t"
                "v_add_f32_dpp %2, %2, %2 row_bcast:15 row_mask:0xa bank_mask:0xf\n\t"
                "v_add_f32_dpp %3, %3, %3 row_bcast:15 row_mask:0xa bank_mask:0xf\n\t"
                "v_add_f32_dpp %0, %0, %0 row_bcast:31 row_mask:0xc bank_mask:0xf\n\t"
                "v_add_f32_dpp %1, %1, %1 row_bcast:31 row_mask:0xc bank_mask:0xf\n\t"
                "v_add_f32_dpp %2, %2, %2 row_bcast:31 row_mask:0xc bank_mask:0xf\n\t"
                "v_add_f32_dpp %3, %3, %3 row_bcast:31 row_mask:0xc bank_mask:0xf\n\t"
                "v_readlane_b32 %4, %0, 63\n\t"
                "v_readlane_b32 %5, %1, 63\n\t"
                "v_readlane_b32 %6, %2, 63\n\t"
                "v_readlane_b32 %7, %3, 63"
                : "+v"(s0), "+v"(s1), "+v"(s2), "+v"(s3),
                  "=s"(tot0), "=s"(tot1), "=s"(tot2), "=s"(tot3));
            asm("v_writelane_b32 %0, %1, %2"
                : "+v"(y_v) : "s"(tot0), "i"(q+0));
            asm("v_writelane_b32 %0, %1, %2"
                : "+v"(y_v) : "s"(tot1), "i"(q+1));
            asm("v_writelane_b32 %0, %1, %2"
                : "+v"(y_v) : "s"(tot2), "i"(q+2));
            asm("v_writelane_b32 %0, %1, %2"
                : "+v"(y_v) : "s"(tot3), "i"(q+3));
        }
        yp[t0 + lane] = fmaf(Dv, xc_v, y_v);
    }
}

extern "C" void kernel_launch(void* const* d_in, const int* in_sizes, int n_in,
                              void* d_out, int out_size, void* d_ws, size_t ws_size,
                              hipStream_t stream)
{
    const float* x        = (const float*)d_in[0];
    const float* norm_w   = (const float*)d_in[1];
    const float* in_projw = (const float*)d_in[2];
    const float* conv_w   = (const float*)d_in[3];
    const float* conv_b   = (const float*)d_in[4];
    const float* x_projw  = (const float*)d_in[5];
    const float* dt_w     = (const float*)d_in[6];
    const float* dt_b     = (const float*)d_in[7];
    const float* A_log    = (const float*)d_in[8];
    const float* D_param  = (const float*)d_in[9];
    const float* out_projw= (const float*)d_in[10];
    float* out = (float*)d_out;

    float* ws   = (float*)d_ws;
    float* rinv = ws;                               // 4096 (pad)
    float* xr   = rinv + 4096;                      // 8M f32
    float* xc   = xr + (size_t)8*1024*1024;         // 4M f32
    float* dtb  = xc + (size_t)4*1024*1024;         // 4M f32 (yt alias)
    float* Bss  = dtb + (size_t)4*1024*1024;        // 128K f32
    float* dtt  = Bss + 131072;                     // 4M f32
    float* xct  = dtt + (size_t)4*1024*1024;        // 4M f32
    ushort* xn_bf  = (ushort*)(xct + (size_t)4*1024*1024); // 2M u16
    ushort* xc_bf  = xn_bf + (size_t)2*1024*1024;          // 4M u16
    ushort* xpw_bf = xc_bf + (size_t)4*1024*1024;          // 128K u16
    // aliases into dead regions:
    ushort* inpw_bf = (ushort*)dtt;   // dead before dtt written
    ushort* dtw_bf  = (ushort*)xct;   // dead before xct written
    ushort* opw_bf  = xn_bf;          // xn dead after GEMM0
    ushort* y_bf    = (ushort*)xc;    // xc dead after transpose
    float* yt = dtb;

    k_rmsfac<<<2048, 256, 0, stream>>>(x, rinv);
    k_cast_xn<<<1024, 256, 0, stream>>>(x, rinv, norm_w, xn_bf);
    k_cast<<<2048, 256, 0, stream>>>(in_projw, inpw_bf, 524288);
    k_mfma<0><<<dim3(32, 16), 256, 0, stream>>>(xn_bf, inpw_bf, nullptr,
                                                xr, nullptr, nullptr, nullptr, 1024, 4096);
    k_conv<<<4096, 256, 0, stream>>>(xr, conv_w, conv_b, xc, xc_bf);
    k_cast<<<2048, 256, 0, stream>>>(dt_w, dtw_bf, 524288);
    k_cast<<<64, 256, 0, stream>>>(x_projw + (size_t)64*2048, xpw_bf, 16384);
    k_mfma<1><<<dim3(17, 16), 256, 0, stream>>>(xc_bf, dtw_bf, xpw_bf,
                                                dtb, Bss, dt_b, nullptr, 2048, 2048);
    k_tr<<<dim3(32, 16, 2), 256, 0, stream>>>(dtb, dtt, DI, L_DIM,
                                              (size_t)L_DIM*DI, (size_t)DI*L_DIM);
    k_tr<<<dim3(32, 16, 2), 256, 0, stream>>>(xc, xct, DI, L_DIM,
                                              (size_t)L_DIM*DI, (size_t)DI*L_DIM);
    k_scan6<<<1024, 256, 0, stream>>>(dtt, xct, Bss, A_log, D_param, yt);
    k_cast<<<1024, 256, 0, stream>>>(out_projw, opw_bf, 262144);
    k_trg<<<dim3(16, 32, 2), 256, 0, stream>>>(yt, xr, y_bf);
    k_mfma<2><<<dim3(8, 16), 256, 0, stream>>>(y_bf, opw_bf, nullptr,
                                               out, nullptr, nullptr, x, 2048, 1024);
}